// Round 7
// baseline (350.020 us; speedup 1.0000x reference)
//
#include <hip/hip_runtime.h>
#include <math.h>
#include <stdint.h>

#define B_    32
#define NT    64
#define NS    48
#define LI    36
#define D_    1024
#define H_    1024
#define NPAIR 1128            // 48*47/2
#define ROWS  (B_*NPAIR)      // 36096 = 141*256
#define NEGV  -9.0e9f

typedef _Float16 half8 __attribute__((ext_vector_type(8)));
typedef float floatx4 __attribute__((ext_vector_type(4)));
typedef __attribute__((address_space(3))) uint32_t lds_u32;
typedef __attribute__((address_space(1))) const uint32_t glb_u32;

#define GLOAD16(src, dst) __builtin_amdgcn_global_load_lds((glb_u32*)(src), (lds_u32*)(dst), 16, 0, 0)

#define MMQ(QR, QC)                                                            \
  {                                                                            \
    _Pragma("unroll") for (int i = 0; i < 4; ++i) {                            \
      _Pragma("unroll") for (int j = 0; j < 2; ++j) {                          \
        acc[QR * 4 + i][QC * 2 + j] = __builtin_amdgcn_mfma_f32_16x16x32_f16(  \
            aF[i][0], bF[j][0], acc[QR * 4 + i][QC * 2 + j], 0, 0, 0);         \
        acc[QR * 4 + i][QC * 2 + j] = __builtin_amdgcn_mfma_f32_16x16x32_f16(  \
            aF[i][1], bF[j][1], acc[QR * 4 + i][QC * 2 + j], 0, 0, 0);         \
      }                                                                        \
    }                                                                          \
  }

// ===========================================================================
// gemm1_8ph: h1[r] = relu((spanH[iF].*spanH[iS]) @ W1cT^T + A1 + B1 + b1)
// 256x256 tile, BK=64, 8 waves, quadrant order (0,0),(1,0),(0,1),(1,1).
// A = product panel, reg-staged (T14) with swizzled ds_write, SINGLE-buffered
// per half (A0 free after P2 -> written P3; A1 free after P3 -> written P0).
// B via global_load_lds, single-buffered per half (B1 loaded P0, read P2/P3;
// B0 loaded P2 for next tile, read P0/P1).  Counted vmcnt, never 0.
// ===========================================================================
__global__ __launch_bounds__(512, 2) void gemm1_8ph(
    const _Float16* __restrict__ spanH, const _Float16* __restrict__ W1cT,
    const float* __restrict__ AB1, const float* __restrict__ b1,
    _Float16* __restrict__ h1out,
    const int* __restrict__ idxF, const int* __restrict__ idxS) {
  // halves: A-half h at h*8192, B-half h at 16384 + h*8192 (in _Float16 units)
  __shared__ __align__(16) _Float16 sP[32768];
  __shared__ int sIF[256], sIS[256];

  const int orig = blockIdx.x;                 // 564 blocks, bijective remap
  const int xcd = orig & 7, pos = orig >> 3;
  const int wg = (xcd < 4 ? xcd * 71 : 284 + (xcd - 4) * 70) + pos;
  const int rowBase = (wg >> 2) * 256;
  const int colBase = (wg & 3) * 256;

  const int t = threadIdx.x;
  const int wave = t >> 6, lane = t & 63;
  const int wq_r = wave >> 2, wq_c = wave & 3;
  const int l15 = lane & 15, l16 = lane >> 4;

  if (t < 256) { sIF[t] = idxF[rowBase + t]; sIS[t] = idxS[rowBase + t]; }
  __syncthreads();

  // staging geometry: thread covers rows srow and 64+srow of a half, slot t&7
  const int srow = t >> 3;
  const int slot = t & 7;
  const int wsw = ((slot ^ (srow & 7)) << 3);   // swizzled slot offset (halves)

  // F/S global row offsets (halves) for both halves' two row groups
  const int oF0a = sIF[srow] << 10,        oF0b = sIF[64 + srow] << 10;
  const int oS0a = sIS[srow] << 10,        oS0b = sIS[64 + srow] << 10;
  const int oF1a = sIF[128 + srow] << 10,  oF1b = sIF[192 + srow] << 10;
  const int oS1a = sIS[128 + srow] << 10,  oS1b = sIS[192 + srow] << 10;
  const int lcol = slot << 3;                   // linear col for reg loads

  const _Float16* gB0a = W1cT + (size_t)(colBase + srow) * D_ + wsw;
  const _Float16* gB0b = W1cT + (size_t)(colBase + 64 + srow) * D_ + wsw;
  const _Float16* gB1a = W1cT + (size_t)(colBase + 128 + srow) * D_ + wsw;
  const _Float16* gB1b = W1cT + (size_t)(colBase + 192 + srow) * D_ + wsw;

  half8 rF0a, rF0b, rS0a, rS0b, rF1a, rF1b, rS1a, rS1b;

  #define ISSUE_FS0(kt) {                                            \
    const int kc = (((kt) & 15) << 6) + lcol;                        \
    rF0a = *(const half8*)(spanH + oF0a + kc);                       \
    rF0b = *(const half8*)(spanH + oF0b + kc);                       \
    rS0a = *(const half8*)(spanH + oS0a + kc);                       \
    rS0b = *(const half8*)(spanH + oS0b + kc); }
  #define ISSUE_FS1(kt) {                                            \
    const int kc = (((kt) & 15) << 6) + lcol;                        \
    rF1a = *(const half8*)(spanH + oF1a + kc);                       \
    rF1b = *(const half8*)(spanH + oF1b + kc);                       \
    rS1a = *(const half8*)(spanH + oS1a + kc);                       \
    rS1b = *(const half8*)(spanH + oS1b + kc); }
  #define WRITE_A0() {                                               \
    *(half8*)(sP + srow * 64 + wsw)        = rF0a * rS0a;            \
    *(half8*)(sP + 4096 + srow * 64 + wsw) = rF0b * rS0b; }
  #define WRITE_A1() {                                               \
    *(half8*)(sP + 8192 + srow * 64 + wsw)  = rF1a * rS1a;           \
    *(half8*)(sP + 12288 + srow * 64 + wsw) = rF1b * rS1b; }
  #define STG_B0(kt) {                                               \
    const int kc = (((kt) & 15) << 6);                               \
    GLOAD16(gB0a + kc, sP + 16384 + t * 8);                          \
    GLOAD16(gB0b + kc, sP + 20480 + t * 8); }
  #define STG_B1(kt) {                                               \
    const int kc = (((kt) & 15) << 6);                               \
    GLOAD16(gB1a + kc, sP + 24576 + t * 8);                          \
    GLOAD16(gB1b + kc, sP + 28672 + t * 8); }

  // fragment reads
  const int rsw = l15 & 7;
  const int aRd = (wq_r * 64 + l15) * 64;
  const int bRd = (wq_c * 32 + l15) * 64;
  const int rd0 = ((l16) ^ rsw) << 3;
  const int rd1 = ((4 + l16) ^ rsw) << 3;
  half8 aF[4][2], bF[2][2];
  floatx4 acc[8][4] = {};
  #define LDA(h) {                                                   \
    const _Float16* p = sP + (h) * 8192 + aRd;                       \
    _Pragma("unroll") for (int i = 0; i < 4; ++i) {                  \
      aF[i][0] = *(const half8*)(p + i * 1024 + rd0);                \
      aF[i][1] = *(const half8*)(p + i * 1024 + rd1); } }
  #define LDB(h) {                                                   \
    const _Float16* p = sP + 16384 + (h) * 8192 + bRd;               \
    _Pragma("unroll") for (int j = 0; j < 2; ++j) {                  \
      bF[j][0] = *(const half8*)(p + j * 1024 + rd0);                \
      bF[j][1] = *(const half8*)(p + j * 1024 + rd1); } }

  // ---- prologue: F0S0(0),F1S1(0),B0(0); write A0(0)
  ISSUE_FS0(0); ISSUE_FS1(0); STG_B0(0);
  asm volatile("s_waitcnt vmcnt(6)" ::: "memory");   // F0S0(0) done
  WRITE_A0();
  asm volatile("s_waitcnt lgkmcnt(0)" ::: "memory");
  __builtin_amdgcn_sched_barrier(0);
  __builtin_amdgcn_s_barrier();

#pragma unroll 1
  for (int kt = 0; kt < 16; ++kt) {
    // ---- P0: Q(0,0).  issue B1(kt), F0S0(kt+1); write A1(kt)
    STG_B1(kt);
    ISSUE_FS0(kt + 1);
    asm volatile("s_waitcnt vmcnt(6)" ::: "memory"); // F1S1(kt), B0(kt) done
    WRITE_A1();
    LDA(0); LDB(0);
    asm volatile("s_waitcnt lgkmcnt(0)" ::: "memory");
    __builtin_amdgcn_sched_barrier(0);
    __builtin_amdgcn_s_barrier();
    __builtin_amdgcn_s_setprio(1);
    MMQ(0, 0);
    __builtin_amdgcn_s_setprio(0);
    __builtin_amdgcn_s_barrier();
    // ---- P1: Q(1,0) reuse B0.  issue F1S1(kt+1)
    ISSUE_FS1(kt + 1);
    LDA(1);
    __builtin_amdgcn_sched_barrier(0);
    __builtin_amdgcn_s_barrier();
    __builtin_amdgcn_s_setprio(1);
    MMQ(1, 0);
    __builtin_amdgcn_s_setprio(0);
    __builtin_amdgcn_s_barrier();
    // ---- P2: Q(0,1).  issue B0(kt+1); wait B1(kt)
    STG_B0(kt + 1);
    asm volatile("s_waitcnt vmcnt(10)" ::: "memory"); // B1(kt) done
    LDA(0); LDB(1);
    __builtin_amdgcn_sched_barrier(0);
    __builtin_amdgcn_s_barrier();
    __builtin_amdgcn_s_setprio(1);
    MMQ(0, 1);
    __builtin_amdgcn_s_setprio(0);
    __builtin_amdgcn_s_barrier();
    // ---- P3: Q(1,1).  wait F0S0(kt+1); write A0(kt+1)
    asm volatile("s_waitcnt vmcnt(6)" ::: "memory");  // F0S0(kt+1) done
    WRITE_A0();
    LDA(1);
    asm volatile("s_waitcnt lgkmcnt(0)" ::: "memory");
    __builtin_amdgcn_sched_barrier(0);
    __builtin_amdgcn_s_barrier();
    __builtin_amdgcn_s_setprio(1);
    MMQ(1, 1);
    __builtin_amdgcn_s_setprio(0);
    __builtin_amdgcn_s_barrier();
  }

  // ---- epilogue: h1 = relu(acc + A1[iF] + B1[iS] + b1), f16
  float bv[2][2];
#pragma unroll
  for (int qc = 0; qc < 2; ++qc)
#pragma unroll
    for (int j = 0; j < 2; ++j)
      bv[qc][j] = b1[colBase + qc * 128 + wq_c * 32 + j * 16 + l15];
#pragma unroll
  for (int qr = 0; qr < 2; ++qr)
#pragma unroll
    for (int i = 0; i < 4; ++i)
#pragma unroll
      for (int q = 0; q < 4; ++q) {
        int rL = qr * 128 + wq_r * 64 + i * 16 + l16 * 4 + q;
        const float* ap = AB1 + (size_t)sIF[rL] * 2048;
        const float* bp = AB1 + (size_t)sIS[rL] * 2048 + 1024;
        size_t ro = (size_t)(rowBase + rL) * 1024;
#pragma unroll
        for (int qc = 0; qc < 2; ++qc)
#pragma unroll
          for (int j = 0; j < 2; ++j) {
            int c = colBase + qc * 128 + wq_c * 32 + j * 16 + l15;
            float v = acc[qr * 4 + i][qc * 2 + j][q] + ap[c] + bp[c] + bv[qc][j];
            h1out[ro + c] = (_Float16)fmaxf(v, 0.f);
          }
      }
}

// ===========================================================================
// gemm2_8ph (unchanged from R6, validated)
// ===========================================================================
__global__ __launch_bounds__(512, 2) void gemm2_8ph(
    const _Float16* __restrict__ Am, const _Float16* __restrict__ Bt,
    float* __restrict__ scores, const float* __restrict__ bias,
    const float* __restrict__ W3) {
  __shared__ __align__(16) _Float16 sP[65536];
  __shared__ float sRed[256][4];

  const int orig = blockIdx.x;
  const int xcd = orig & 7, pos = orig >> 3;
  const int wg = (xcd < 4 ? xcd * 71 : 284 + (xcd - 4) * 70) + pos;
  const int rowBase = (wg >> 2) * 256;
  const int colBase = (wg & 3) * 256;

  const int t = threadIdx.x;
  const int wave = t >> 6, lane = t & 63;
  const int wq_r = wave >> 2, wq_c = wave & 3;
  const int l15 = lane & 15, l16 = lane >> 4;
  const int sxor = l15 & 7;

  const int srow0 = t >> 3, srow1 = (512 + t) >> 3;
  const int lcol0 = ((t & 7) ^ (srow0 & 7)) << 3;
  const int lcol1 = (((512 + t) & 7) ^ (srow1 & 7)) << 3;
  const _Float16* aS0 = Am + (size_t)(rowBase + srow0) * D_ + lcol0;
  const _Float16* aS1 = Am + (size_t)(rowBase + srow1) * D_ + lcol1;
  const _Float16* bS0 = Bt + (size_t)(colBase + srow0) * D_ + lcol0;
  const _Float16* bS1 = Bt + (size_t)(colBase + srow1) * D_ + lcol1;

  auto stgA = [&](int kt, int h) {
    const int db = kt & 1;
    const size_t so = (size_t)(kt & 15) * 64 + (size_t)h * 128 * D_;
    _Float16* d = sP + ((db << 1) + h) * 8192;
    GLOAD16(aS0 + so, d + t * 8);
    GLOAD16(aS1 + so, d + 4096 + t * 8);
  };
  auto stgB = [&](int kt, int h) {
    const int db = kt & 1;
    const size_t so = (size_t)(kt & 15) * 64 + (size_t)h * 128 * D_;
    _Float16* d = sP + 32768 + ((db << 1) + h) * 8192;
    GLOAD16(bS0 + so, d + t * 8);
    GLOAD16(bS1 + so, d + 4096 + t * 8);
  };

  const int aRdRow = (wq_r * 64 + l15) * 64;
  const int bRdRow = (wq_c * 32 + l15) * 64;
  const int rdSlot0 = ((l16) ^ sxor) << 3;
  const int rdSlot1 = ((4 + l16) ^ sxor) << 3;

  half8 aF[4][2], bF[2][2];
  floatx4 acc[8][4] = {};

  auto ldA = [&](int db, int qr) {
    const _Float16* p = sP + ((db << 1) + qr) * 8192 + aRdRow;
#pragma unroll
    for (int i = 0; i < 4; ++i) {
      aF[i][0] = *(const half8*)(p + i * 1024 + rdSlot0);
      aF[i][1] = *(const half8*)(p + i * 1024 + rdSlot1);
    }
  };
  auto ldB = [&](int db, int qc) {
    const _Float16* p = sP + 32768 + ((db << 1) + qc) * 8192 + bRdRow;
#pragma unroll
    for (int j = 0; j < 2; ++j) {
      bF[j][0] = *(const half8*)(p + j * 1024 + rdSlot0);
      bF[j][1] = *(const half8*)(p + j * 1024 + rdSlot1);
    }
  };

  stgB(0, 0); stgA(0, 1); stgA(0, 0); stgB(0, 1); stgB(1, 0); stgA(1, 1);
  asm volatile("s_waitcnt vmcnt(4)" ::: "memory");
  __builtin_amdgcn_s_barrier();

#pragma unroll 1
  for (int kt = 0; kt < 16; ++kt) {
    const int db = kt & 1;
    const int kn1 = kt + 1, kn2 = kt + 2;
    ldA(db, 0); ldB(db, 0);
    stgA(kn1, 0);
    __builtin_amdgcn_sched_barrier(0);
    __builtin_amdgcn_s_barrier();
    __builtin_amdgcn_s_setprio(1);
    MMQ(0, 0);
    __builtin_amdgcn_s_setprio(0);
    __builtin_amdgcn_s_barrier();
    ldA(db, 1);
    stgB(kn1, 1);
    __builtin_amdgcn_sched_barrier(0);
    __builtin_amdgcn_s_barrier();
    __builtin_amdgcn_s_setprio(1);
    MMQ(1, 0);
    __builtin_amdgcn_s_setprio(0);
    __builtin_amdgcn_s_barrier();
    ldB(db, 1);
    stgB(kn2, 0);
    __builtin_amdgcn_sched_barrier(0);
    __builtin_amdgcn_s_barrier();
    __builtin_amdgcn_s_setprio(1);
    MMQ(1, 1);
    __builtin_amdgcn_s_setprio(0);
    __builtin_amdgcn_s_barrier();
    ldA(db, 0);
    stgA(kn2, 1);
    __builtin_amdgcn_sched_barrier(0);
    asm volatile("s_waitcnt vmcnt(4)" ::: "memory");
    __builtin_amdgcn_s_barrier();
    __builtin_amdgcn_s_setprio(1);
    MMQ(0, 1);
    __builtin_amdgcn_s_setprio(0);
    __builtin_amdgcn_s_barrier();
  }

  float bv[2][2], wv[2][2];
#pragma unroll
  for (int qc = 0; qc < 2; ++qc)
#pragma unroll
    for (int j = 0; j < 2; ++j) {
      int c = colBase + qc * 128 + wq_c * 32 + j * 16 + l15;
      bv[qc][j] = bias[c];
      wv[qc][j] = W3[c];
    }
#pragma unroll
  for (int qr = 0; qr < 2; ++qr)
#pragma unroll
    for (int i = 0; i < 4; ++i)
#pragma unroll
      for (int q = 0; q < 4; ++q) {
        float s = 0.f;
#pragma unroll
        for (int qc = 0; qc < 2; ++qc)
#pragma unroll
          for (int j = 0; j < 2; ++j)
            s += fmaxf(acc[qr * 4 + i][qc * 2 + j][q] + bv[qc][j], 0.f) * wv[qc][j];
        s += __shfl_xor(s, 1); s += __shfl_xor(s, 2);
        s += __shfl_xor(s, 4); s += __shfl_xor(s, 8);
        if (l15 == 0)
          sRed[qr * 128 + wq_r * 64 + i * 16 + l16 * 4 + q][wq_c] = s;
      }
  __syncthreads();
  if (t < 256)
    atomicAdd(&scores[rowBase + t],
              sRed[t][0] + sRed[t][1] + sRed[t][2] + sRed[t][3]);
}

// ===========================================================================
// Shared 128x128 EPI-0 GEMM body (2-phase, gload_lds, slot-XOR swizzle)
// ===========================================================================
__device__ __forceinline__ void gemm_body(
    const _Float16* __restrict__ A, const _Float16* __restrict__ Bt,
    float* __restrict__ Cf, int N, int K, int rowBase, int colBase) {
  __shared__ __align__(16) _Float16 sA[8192];
  __shared__ __align__(16) _Float16 sB[8192];
  const int tid = threadIdx.x;
  const int lane = tid & 63;
  const int wave = tid >> 6;
  const int wr = wave >> 1, wc = wave & 1;
  const int l15 = lane & 15, l16 = lane >> 4;
  const int rsw = (l15 >> 1) & 3;
  const int sRow = tid >> 2;
  const int swz8 = (((tid & 3) ^ ((tid >> 3) & 3)) << 3);
  const _Float16* gA = A + (size_t)(rowBase + sRow) * K + swz8;
  const _Float16* gB = Bt + (size_t)(colBase + sRow) * K + swz8;
  _Float16* lA = sA + tid * 8;
  _Float16* lB = sB + tid * 8;

  floatx4 acc[4][4] = {};
  for (int k0 = 0; k0 < K; k0 += 64) {
    GLOAD16(gA + k0,               lA);
    GLOAD16(gA + 64 * K + k0,      lA + 2048);
    GLOAD16(gA + k0 + 32,          lA + 4096);
    GLOAD16(gA + 64 * K + k0 + 32, lA + 6144);
    GLOAD16(gB + k0,               lB);
    GLOAD16(gB + 64 * K + k0,      lB + 2048);
    GLOAD16(gB + k0 + 32,          lB + 4096);
    GLOAD16(gB + 64 * K + k0 + 32, lB + 6144);
    __syncthreads();
#pragma unroll
    for (int h = 0; h < 2; ++h) {
      const int hb = h * 4096;
      half8 aF[4], bF[4];
#pragma unroll
      for (int i = 0; i < 4; ++i)
        aF[i] = *(const half8*)&sA[hb + (wr * 64 + i * 16 + l15) * 32 + ((l16 ^ rsw) << 3)];
#pragma unroll
      for (int j = 0; j < 4; ++j)
        bF[j] = *(const half8*)&sB[hb + (wc * 64 + j * 16 + l15) * 32 + ((l16 ^ rsw) << 3)];
#pragma unroll
      for (int i = 0; i < 4; ++i)
#pragma unroll
        for (int j = 0; j < 4; ++j)
          acc[i][j] = __builtin_amdgcn_mfma_f32_16x16x32_f16(aF[i], bF[j], acc[i][j], 0, 0, 0);
    }
    __syncthreads();
  }
#pragma unroll
  for (int i = 0; i < 4; ++i)
#pragma unroll
    for (int q = 0; q < 4; ++q) {
      int r = rowBase + wr * 64 + i * 16 + l16 * 4 + q;
#pragma unroll
      for (int j = 0; j < 4; ++j) {
        int c = colBase + wc * 64 + j * 16 + l15;
        Cf[(size_t)r * N + c] = acc[i][j][q];
      }
    }
}

__global__ __launch_bounds__(256) void gemm_trio(
    const _Float16* __restrict__ textH, const _Float16* __restrict__ imgH,
    const _Float16* __restrict__ spanH, const _Float16* __restrict__ W1abT,
    float* __restrict__ dotTI, float* __restrict__ dotSI, float* __restrict__ AB1) {
  int bid = blockIdx.x;
  if (bid < 144)      gemm_body(textH, imgH, dotTI, 1152, D_, (bid / 9) * 128, (bid % 9) * 128);
  else if (bid < 252) { int b = bid - 144; gemm_body(spanH, imgH, dotSI, 1152, D_, (b / 9) * 128, (b % 9) * 128); }
  else                { int b = bid - 252; gemm_body(spanH, W1abT, AB1, 2048, D_, (b / 16) * 128, (b % 16) * 128); }
}

// ===========================================================================
// prep / small kernels
// ===========================================================================
__global__ __launch_bounds__(256) void cvt_all(
    const float* __restrict__ text, const float* __restrict__ span,
    const float* __restrict__ img, _Float16* __restrict__ textH,
    _Float16* __restrict__ spanH, _Float16* __restrict__ imgH) {
  long long i = (long long)blockIdx.x * 256 + threadIdx.x;
  const float* src; _Float16* dst; long long off;
  if (i < 262144)      { src = text; dst = textH; off = i; }
  else if (i < 458752) { src = span; dst = spanH; off = i - 262144; }
  else if (i < 606208) { src = img;  dst = imgH;  off = i - 458752; }
  else return;
  const float4* p = (const float4*)src + off * 2;
  float4 a = p[0], b = p[1];
  half8 h;
  h[0] = (_Float16)a.x; h[1] = (_Float16)a.y; h[2] = (_Float16)a.z; h[3] = (_Float16)a.w;
  h[4] = (_Float16)b.x; h[5] = (_Float16)b.y; h[6] = (_Float16)b.z; h[7] = (_Float16)b.w;
  *(half8*)(dst + off * 8) = h;
}

__global__ __launch_bounds__(256) void transpose_all(
    const float* __restrict__ W1, const float* __restrict__ W2,
    _Float16* __restrict__ W1abT, _Float16* __restrict__ W1cT,
    _Float16* __restrict__ W2T) {
  __shared__ float tbuf[32][33];
  const float* in; _Float16* out;
  switch (blockIdx.z) {
    case 0: in = W1;                 out = W1abT;                 break;
    case 1: in = W1 + 1024 * 1024;   out = W1abT + 1024 * 1024;   break;
    case 2: in = W1 + 2048 * 1024;   out = W1cT;                  break;
    default: in = W2;                out = W2T;                   break;
  }
  const int tx = threadIdx.x & 31, ty = threadIdx.x >> 5;
  const int k0 = blockIdx.y * 32, n0 = blockIdx.x * 32;
#pragma unroll
  for (int q = 0; q < 4; ++q)
    tbuf[ty + q * 8][tx] = in[(size_t)(k0 + ty + q * 8) * 1024 + n0 + tx];
  __syncthreads();
#pragma unroll
  for (int q = 0; q < 4; ++q)
    out[(size_t)(n0 + ty + q * 8) * 1024 + k0 + tx] = (_Float16)tbuf[tx][ty + q * 8];
}

__global__ __launch_bounds__(256) void idx_init(int* __restrict__ idxF, int* __restrict__ idxS) {
  int r = blockIdx.x * 256 + threadIdx.x;
  if (r >= ROWS) return;
  int bb = r / NPAIR, p = r - bb * NPAIR;
  int cum = 0, f = 0;
  while (true) { int cnt = NS - 1 - f; if (p < cum + cnt) break; cum += cnt; ++f; }
  idxF[r] = bb * NS + f;
  idxS[r] = bb * NS + f + 1 + (p - cum);
}

__global__ void init_scores(float* __restrict__ scores, const float* __restrict__ b3) {
  int idx = blockIdx.x * 256 + threadIdx.x;
  if (idx < ROWS) scores[idx] = b3[0];
}

__global__ __launch_bounds__(256) void extract_grounding(
    const float* __restrict__ dotSI, const float* __restrict__ smask,
    const float* __restrict__ imask, float* __restrict__ outg) {
  int idx = blockIdx.x * 256 + threadIdx.x;
  if (idx >= B_ * NS * LI) return;
  int b = idx / (NS * LI);
  int rem = idx - b * (NS * LI);
  int n = rem / LI, l = rem - n * LI;
  float v = dotSI[(size_t)(b * NS + n) * (B_ * LI) + b * LI + l];
  outg[idx] = (smask[b * NS + n] * imask[b * LI + l] != 0.f) ? v : NEGV;
}

__global__ __launch_bounds__(64) void sent_kernel(
    const float* __restrict__ dotTI, const float* __restrict__ tmask,
    const float* __restrict__ imask, float* __restrict__ S) {
  const int i = blockIdx.y, j = blockIdx.x, t = threadIdx.x;
  __shared__ float red1[64], red2[64];
  const int stride = B_ * LI;
  float e1 = 0.f;
  {
    float tm = tmask[i * NT + t];
    if (tm != 0.f) {
      const float* row = dotTI + (size_t)(i * NT + t) * stride + j * LI;
      float m = -INFINITY;
      for (int l = 0; l < LI; ++l) if (imask[j * LI + l] != 0.f) m = fmaxf(m, row[l]);
      float z = 0.f, w = 0.f;
      for (int l = 0; l < LI; ++l) if (imask[j * LI + l] != 0.f) {
        float d = row[l], p = expf(d - m);
        z += p; w += p * d;
      }
      e1 = w / z;
    }
  }
  red1[t] = e1;
  float e2 = 0.f;
  if (t < LI) {
    float im = imask[j * LI + t];
    if (im != 0.f) {
      const float* col = dotTI + (size_t)(i * NT) * stride + j * LI + t;
      float m = -INFINITY;
      for (int n = 0; n < NT; ++n) if (tmask[i * NT + n] != 0.f) m = fmaxf(m, col[(size_t)n * stride]);
      float z = 0.f, w = 0.f;
      for (int n = 0; n < NT; ++n) if (tmask[i * NT + n] != 0.f) {
        float d = col[(size_t)n * stride], p = expf(d - m);
        z += p; w += p * d;
      }
      e2 = w / z;
    }
  }
  red2[t] = e2;
  __syncthreads();
  if (t == 0) {
    float s1 = 0.f, s2 = 0.f, cn = 0.f, cl = 0.f;
    for (int n = 0; n < NT; ++n) { s1 += red1[n]; cn += tmask[i * NT + n]; }
    for (int l = 0; l < LI; ++l) { s2 += red2[l]; cl += imask[j * LI + l]; }
    S[i * B_ + j] = s1 / cn + s2 / cl;
  }
}

__global__ __launch_bounds__(64) void loss_kernel(
    const float* __restrict__ S, float* __restrict__ out) {
  __shared__ float sS[B_][B_ + 1];
  __shared__ float acc[B_];
  const int t = threadIdx.x;
  for (int e = t; e < B_ * B_; e += 64) sS[e / B_][e % B_] = S[e];
  __syncthreads();
  if (t < B_) {
    float m = -INFINITY;
    for (int j = 0; j < B_; ++j) m = fmaxf(m, sS[t][j]);
    float z = 0.f;
    for (int j = 0; j < B_; ++j) z += expf(sS[t][j] - m);
    float lr = m + logf(z);
    float m2 = -INFINITY;
    for (int i = 0; i < B_; ++i) m2 = fmaxf(m2, sS[i][t]);
    float z2 = 0.f;
    for (int i = 0; i < B_; ++i) z2 += expf(sS[i][t] - m2);
    float lc = m2 + logf(z2);
    acc[t] = 2.f * sS[t][t] - lr - lc;
  }
  __syncthreads();
  if (t == 0) {
    float s = 0.f;
    for (int i = 0; i < B_; ++i) s += acc[i];
    out[0] = -s / (float)B_;
  }
}

extern "C" void kernel_launch(void* const* d_in, const int* in_sizes, int n_in,
                              void* d_out, int out_size, void* d_ws, size_t ws_size,
                              hipStream_t stream) {
  const float* text  = (const float*)d_in[0];
  const float* span  = (const float*)d_in[1];
  const float* img   = (const float*)d_in[2];
  const float* tmask = (const float*)d_in[3];
  const float* smask = (const float*)d_in[4];
  const float* imask = (const float*)d_in[5];
  const float* W1    = (const float*)d_in[6];
  const float* b1    = (const float*)d_in[7];
  const float* W2    = (const float*)d_in[8];
  const float* b2    = (const float*)d_in[9];
  const float* W3    = (const float*)d_in[10];
  const float* b3    = (const float*)d_in[11];

  float* out     = (float*)d_out;
  float* outLoss = out;
  float* outG    = out + 1;
  float* outT    = out + 1 + (size_t)B_ * NS * LI;

  // ---- workspace layout ----
  char* w = (char*)d_ws;
  float*    dotTI = (float*)w;            w += (size_t)(B_*NT) * (B_*LI) * 4;
  float*    dotSI = (float*)w;            w += (size_t)(B_*NS) * (B_*LI) * 4;
  float*    S     = (float*)w;            w += 1024 * 4;
  float*    AB1   = (float*)w;            w += (size_t)1536 * 2048 * 4;
  _Float16* h1    = (_Float16*)w;         w += (size_t)ROWS * 1024 * 2;
  _Float16* textH = (_Float16*)w;         w += (size_t)2048 * 1024 * 2;
  _Float16* spanH = (_Float16*)w;         w += (size_t)1536 * 1024 * 2;
  _Float16* imgH  = (_Float16*)w;         w += (size_t)1152 * 1024 * 2;
  _Float16* W1abT = (_Float16*)w;         w += (size_t)2048 * 1024 * 2;
  _Float16* W1cT  = (_Float16*)w;         w += (size_t)1024 * 1024 * 2;
  _Float16* W2T   = (_Float16*)w;         w += (size_t)1024 * 1024 * 2;
  int*      idxF  = (int*)w;              w += ROWS * 4;
  int*      idxS  = (int*)w;              w += ROWS * 4;
  (void)ws_size; (void)in_sizes; (void)n_in; (void)out_size;

  // ---- prep ----
  cvt_all<<<(606208 + 255) / 256, 256, 0, stream>>>(text, span, img, textH, spanH, imgH);
  transpose_all<<<dim3(32, 32, 4), 256, 0, stream>>>(W1, W2, W1abT, W1cT, W2T);
  idx_init<<<(ROWS + 255) / 256, 256, 0, stream>>>(idxF, idxS);

  // ---- small GEMMs merged: dotTI, dotSI, AB1 ----
  gemm_trio<<<444, 256, 0, stream>>>(textH, imgH, spanH, W1abT, dotTI, dotSI, AB1);
  sent_kernel<<<dim3(B_, B_), 64, 0, stream>>>(dotTI, tmask, imask, S);
  loss_kernel<<<1, 64, 0, stream>>>(S, outLoss);
  extract_grounding<<<(B_*NS*LI + 255) / 256, 256, 0, stream>>>(dotSI, smask, imask, outG);

  // ---- pairwise MLP ----
  gemm1_8ph<<<564, 512, 0, stream>>>(spanH, W1cT, AB1, b1, h1, idxF, idxS);
  init_scores<<<(ROWS + 255) / 256, 256, 0, stream>>>(outT, b3);
  gemm2_8ph<<<564, 512, 0, stream>>>(h1, W2T, outT, b2, W3);
}

// Round 8
// 344.807 us; speedup vs baseline: 1.0151x; 1.0151x over previous
//
#include <hip/hip_runtime.h>
#include <math.h>
#include <stdint.h>

#define B_    32
#define NT    64
#define NS    48
#define LI    36
#define D_    1024
#define H_    1024
#define NPAIR 1128            // 48*47/2
#define ROWS  (B_*NPAIR)      // 36096 = 141*256
#define NEGV  -9.0e9f

typedef _Float16 half8 __attribute__((ext_vector_type(8)));
typedef float floatx4 __attribute__((ext_vector_type(4)));
typedef __attribute__((address_space(3))) uint32_t lds_u32;
typedef __attribute__((address_space(1))) const uint32_t glb_u32;

#define GLOAD16(src, dst) __builtin_amdgcn_global_load_lds((glb_u32*)(src), (lds_u32*)(dst), 16, 0, 0)

#define MMQ(QR, QC)                                                            \
  {                                                                            \
    _Pragma("unroll") for (int i = 0; i < 4; ++i) {                            \
      _Pragma("unroll") for (int j = 0; j < 2; ++j) {                          \
        acc[QR * 4 + i][QC * 2 + j] = __builtin_amdgcn_mfma_f32_16x16x32_f16(  \
            aF[i][0], bF[j][0], acc[QR * 4 + i][QC * 2 + j], 0, 0, 0);         \
        acc[QR * 4 + i][QC * 2 + j] = __builtin_amdgcn_mfma_f32_16x16x32_f16(  \
            aF[i][1], bF[j][1], acc[QR * 4 + i][QC * 2 + j], 0, 0, 0);         \
      }                                                                        \
    }                                                                          \
  }

// ===========================================================================
// gemm1_8ph v2: h1 = relu((spanH[iF].*spanH[iS]) @ W1cT^T + A1 + B1 + b1)
// Faithful gemm2_8ph skeleton (ds_reads FIRST in each phase, gray quadrant
// order, one manual vmcnt per tile).  A and B fully DOUBLE-buffered (128 KB).
// A-product reg-staged with 4-phase leads (compiler auto-waits are ~free);
// B via global_load_lds drained by vmcnt(8) at P3.  Never drains to 0.
// ===========================================================================
__global__ __launch_bounds__(512, 2) void gemm1_8ph(
    const _Float16* __restrict__ spanH, const _Float16* __restrict__ W1cT,
    const float* __restrict__ AB1, const float* __restrict__ b1,
    _Float16* __restrict__ h1out,
    const int* __restrict__ idxF, const int* __restrict__ idxS) {
  // A: [db][h] panels at ((db*2+h)*8192); B at 32768 + same.  (halves)
  __shared__ __align__(16) _Float16 sP[65536];
  __shared__ int sIF[256], sIS[256];

  const int orig = blockIdx.x;                 // 564 blocks, bijective remap
  const int xcd = orig & 7, pos = orig >> 3;
  const int wg = (xcd < 4 ? xcd * 71 : 284 + (xcd - 4) * 70) + pos;
  const int rowBase = (wg >> 2) * 256;
  const int colBase = (wg & 3) * 256;

  const int t = threadIdx.x;
  const int wave = t >> 6, lane = t & 63;
  const int wq_r = wave >> 2, wq_c = wave & 3;
  const int l15 = lane & 15, l16 = lane >> 4;
  const int sxor = l15 & 7;

  if (t < 256) { sIF[t] = idxF[rowBase + t]; sIS[t] = idxS[rowBase + t]; }
  __syncthreads();

  // ---- A-product staging geometry (each thread: rows srow, 64+srow of a half)
  const int srow = t >> 3;
  const int slot = t & 7;
  const int wsw = ((slot ^ (srow & 7)) << 3);   // swizzled slot offset
  const int lcol = slot << 3;                   // linear global col for reg loads
  const int oF0a = sIF[srow] << 10,       oF0b = sIF[64 + srow] << 10;
  const int oS0a = sIS[srow] << 10,       oS0b = sIS[64 + srow] << 10;
  const int oF1a = sIF[128 + srow] << 10, oF1b = sIF[192 + srow] << 10;
  const int oS1a = sIS[128 + srow] << 10, oS1b = sIS[192 + srow] << 10;

  half8 rF0a, rF0b, rS0a, rS0b, rF1a, rF1b, rS1a, rS1b;

  #define ISSUE_FS0(kt) {                                            \
    const int kc = (((kt) & 15) << 6) + lcol;                        \
    rF0a = *(const half8*)(spanH + oF0a + kc);                       \
    rF0b = *(const half8*)(spanH + oF0b + kc);                       \
    rS0a = *(const half8*)(spanH + oS0a + kc);                       \
    rS0b = *(const half8*)(spanH + oS0b + kc); }
  #define ISSUE_FS1(kt) {                                            \
    const int kc = (((kt) & 15) << 6) + lcol;                        \
    rF1a = *(const half8*)(spanH + oF1a + kc);                       \
    rF1b = *(const half8*)(spanH + oF1b + kc);                       \
    rS1a = *(const half8*)(spanH + oS1a + kc);                       \
    rS1b = *(const half8*)(spanH + oS1b + kc); }
  #define WRITE_A0(kt) {                                             \
    _Float16* d = sP + ((((kt) & 1) << 1) + 0) * 8192;               \
    *(half8*)(d + srow * 64 + wsw)        = rF0a * rS0a;             \
    *(half8*)(d + 4096 + srow * 64 + wsw) = rF0b * rS0b; }
  #define WRITE_A1(kt) {                                             \
    _Float16* d = sP + ((((kt) & 1) << 1) + 1) * 8192;               \
    *(half8*)(d + srow * 64 + wsw)        = rF1a * rS1a;             \
    *(half8*)(d + 4096 + srow * 64 + wsw) = rF1b * rS1b; }

  // ---- B staging (global_load_lds, pre-swizzled source, gemm2 pattern)
  const int srow0 = t >> 3, srow1 = 64 + (t >> 3);
  const int lcol0 = ((t & 7) ^ (srow0 & 7)) << 3;
  const int lcol1 = ((t & 7) ^ (srow1 & 7)) << 3;
  const _Float16* bS0 = W1cT + (size_t)(colBase + srow0) * D_ + lcol0;
  const _Float16* bS1 = W1cT + (size_t)(colBase + srow1) * D_ + lcol1;
  #define STG_B(kt, h) {                                             \
    const size_t so = (size_t)((kt) & 15) * 64 + (size_t)(h) * 128 * D_; \
    _Float16* d = sP + 32768 + ((((kt) & 1) << 1) + (h)) * 8192;     \
    GLOAD16(bS0 + so, d + t * 8);                                    \
    GLOAD16(bS1 + so, d + 4096 + t * 8); }

  // ---- fragment reads (identical to gemm2_8ph)
  const int aRdRow = (wq_r * 64 + l15) * 64;
  const int bRdRow = (wq_c * 32 + l15) * 64;
  const int rd0 = ((l16) ^ sxor) << 3;
  const int rd1 = ((4 + l16) ^ sxor) << 3;
  half8 aF[4][2], bF[2][2];
  floatx4 acc[8][4] = {};
  #define LDA(db, h) {                                               \
    const _Float16* p = sP + (((db) << 1) + (h)) * 8192 + aRdRow;    \
    _Pragma("unroll") for (int i = 0; i < 4; ++i) {                  \
      aF[i][0] = *(const half8*)(p + i * 1024 + rd0);                \
      aF[i][1] = *(const half8*)(p + i * 1024 + rd1); } }
  #define LDB(db, h) {                                               \
    const _Float16* p = sP + 32768 + (((db) << 1) + (h)) * 8192 + bRdRow; \
    _Pragma("unroll") for (int j = 0; j < 2; ++j) {                  \
      bF[j][0] = *(const half8*)(p + j * 1024 + rd0);                \
      bF[j][1] = *(const half8*)(p + j * 1024 + rd1); } }

  // ---- prologue: prime A(0), B(0), FS(1); drain B(0); never to 0
  ISSUE_FS0(0); ISSUE_FS1(0);
  STG_B(0, 0); STG_B(0, 1);
  WRITE_A0(0);                      // compiler auto-wait on FS0(0)
  WRITE_A1(0);                      // auto-wait on FS1(0)
  ISSUE_FS0(1); ISSUE_FS1(1);
  asm volatile("s_waitcnt vmcnt(8)" ::: "memory");   // drain B(0,*)
  asm volatile("s_waitcnt lgkmcnt(0)" ::: "memory");
  __builtin_amdgcn_sched_barrier(0);
  __builtin_amdgcn_s_barrier();

#pragma unroll 1
  for (int kt = 0; kt < 16; ++kt) {
    const int db = kt & 1;
    // ---- P0: Q(0,0) [A0,B0]; issue B(kt+1,0)
    LDA(db, 0); LDB(db, 0);
    STG_B(kt + 1, 0);
    __builtin_amdgcn_sched_barrier(0);
    __builtin_amdgcn_s_barrier();
    __builtin_amdgcn_s_setprio(1);
    MMQ(0, 0);
    __builtin_amdgcn_s_setprio(0);
    __builtin_amdgcn_s_barrier();
    // ---- P1: Q(1,0) [A1,B0]; issue B(kt+1,1)
    LDA(db, 1);
    STG_B(kt + 1, 1);
    __builtin_amdgcn_sched_barrier(0);
    __builtin_amdgcn_s_barrier();
    __builtin_amdgcn_s_setprio(1);
    MMQ(1, 0);
    __builtin_amdgcn_s_setprio(0);
    __builtin_amdgcn_s_barrier();
    // ---- P2: Q(1,1) [A1 kept, B1]; write A0(kt+1); issue FS0(kt+2)
    WRITE_A0(kt + 1);               // auto-wait on FS0(kt+1) (~free, 4-ph lead)
    ISSUE_FS0(kt + 2);
    LDB(db, 1);
    __builtin_amdgcn_sched_barrier(0);
    __builtin_amdgcn_s_barrier();
    __builtin_amdgcn_s_setprio(1);
    MMQ(1, 1);
    __builtin_amdgcn_s_setprio(0);
    __builtin_amdgcn_s_barrier();
    // ---- P3: Q(0,1) [A0 reload, B1]; write A1(kt+1); issue FS1(kt+2);
    //          single manual drain: vmcnt(8) -> B(kt+1,0), B(kt+1,1) done
    WRITE_A1(kt + 1);               // auto-wait on FS1(kt+1)
    ISSUE_FS1(kt + 2);
    LDA(db, 0);
    asm volatile("s_waitcnt vmcnt(8)" ::: "memory");
    asm volatile("s_waitcnt lgkmcnt(0)" ::: "memory");
    __builtin_amdgcn_sched_barrier(0);
    __builtin_amdgcn_s_barrier();
    __builtin_amdgcn_s_setprio(1);
    MMQ(0, 1);
    __builtin_amdgcn_s_setprio(0);
    __builtin_amdgcn_s_barrier();
  }

  // ---- epilogue: h1 = relu(acc + A1[iF] + B1[iS] + b1), f16 (R7-verified)
  float bv[2][2];
#pragma unroll
  for (int qc = 0; qc < 2; ++qc)
#pragma unroll
    for (int j = 0; j < 2; ++j)
      bv[qc][j] = b1[colBase + qc * 128 + wq_c * 32 + j * 16 + l15];
#pragma unroll
  for (int qr = 0; qr < 2; ++qr)
#pragma unroll
    for (int i = 0; i < 4; ++i)
#pragma unroll
      for (int q = 0; q < 4; ++q) {
        int rL = qr * 128 + wq_r * 64 + i * 16 + l16 * 4 + q;
        const float* ap = AB1 + (size_t)sIF[rL] * 2048;
        const float* bp = AB1 + (size_t)sIS[rL] * 2048 + 1024;
        size_t ro = (size_t)(rowBase + rL) * 1024;
#pragma unroll
        for (int qc = 0; qc < 2; ++qc)
#pragma unroll
          for (int j = 0; j < 2; ++j) {
            int c = colBase + qc * 128 + wq_c * 32 + j * 16 + l15;
            float v = acc[qr * 4 + i][qc * 2 + j][q] + ap[c] + bp[c] + bv[qc][j];
            h1out[ro + c] = (_Float16)fmaxf(v, 0.f);
          }
      }
}

// ===========================================================================
// gemm2_8ph (unchanged, validated)
// ===========================================================================
__global__ __launch_bounds__(512, 2) void gemm2_8ph(
    const _Float16* __restrict__ Am, const _Float16* __restrict__ Bt,
    float* __restrict__ scores, const float* __restrict__ bias,
    const float* __restrict__ W3) {
  __shared__ __align__(16) _Float16 sP[65536];
  __shared__ float sRed[256][4];

  const int orig = blockIdx.x;
  const int xcd = orig & 7, pos = orig >> 3;
  const int wg = (xcd < 4 ? xcd * 71 : 284 + (xcd - 4) * 70) + pos;
  const int rowBase = (wg >> 2) * 256;
  const int colBase = (wg & 3) * 256;

  const int t = threadIdx.x;
  const int wave = t >> 6, lane = t & 63;
  const int wq_r = wave >> 2, wq_c = wave & 3;
  const int l15 = lane & 15, l16 = lane >> 4;
  const int sxor = l15 & 7;

  const int srow0 = t >> 3, srow1 = (512 + t) >> 3;
  const int lcol0 = ((t & 7) ^ (srow0 & 7)) << 3;
  const int lcol1 = (((512 + t) & 7) ^ (srow1 & 7)) << 3;
  const _Float16* aS0 = Am + (size_t)(rowBase + srow0) * D_ + lcol0;
  const _Float16* aS1 = Am + (size_t)(rowBase + srow1) * D_ + lcol1;
  const _Float16* bS0 = Bt + (size_t)(colBase + srow0) * D_ + lcol0;
  const _Float16* bS1 = Bt + (size_t)(colBase + srow1) * D_ + lcol1;

  auto stgA = [&](int kt, int h) {
    const int db = kt & 1;
    const size_t so = (size_t)(kt & 15) * 64 + (size_t)h * 128 * D_;
    _Float16* d = sP + ((db << 1) + h) * 8192;
    GLOAD16(aS0 + so, d + t * 8);
    GLOAD16(aS1 + so, d + 4096 + t * 8);
  };
  auto stgB = [&](int kt, int h) {
    const int db = kt & 1;
    const size_t so = (size_t)(kt & 15) * 64 + (size_t)h * 128 * D_;
    _Float16* d = sP + 32768 + ((db << 1) + h) * 8192;
    GLOAD16(bS0 + so, d + t * 8);
    GLOAD16(bS1 + so, d + 4096 + t * 8);
  };

  const int aRdRow = (wq_r * 64 + l15) * 64;
  const int bRdRow = (wq_c * 32 + l15) * 64;
  const int rdSlot0 = ((l16) ^ sxor) << 3;
  const int rdSlot1 = ((4 + l16) ^ sxor) << 3;

  half8 aF[4][2], bF[2][2];
  floatx4 acc[8][4] = {};

  auto ldA = [&](int db, int qr) {
    const _Float16* p = sP + ((db << 1) + qr) * 8192 + aRdRow;
#pragma unroll
    for (int i = 0; i < 4; ++i) {
      aF[i][0] = *(const half8*)(p + i * 1024 + rdSlot0);
      aF[i][1] = *(const half8*)(p + i * 1024 + rdSlot1);
    }
  };
  auto ldB = [&](int db, int qc) {
    const _Float16* p = sP + 32768 + ((db << 1) + qc) * 8192 + bRdRow;
#pragma unroll
    for (int j = 0; j < 2; ++j) {
      bF[j][0] = *(const half8*)(p + j * 1024 + rdSlot0);
      bF[j][1] = *(const half8*)(p + j * 1024 + rdSlot1);
    }
  };

  stgB(0, 0); stgA(0, 1); stgA(0, 0); stgB(0, 1); stgB(1, 0); stgA(1, 1);
  asm volatile("s_waitcnt vmcnt(4)" ::: "memory");
  __builtin_amdgcn_s_barrier();

#pragma unroll 1
  for (int kt = 0; kt < 16; ++kt) {
    const int db = kt & 1;
    const int kn1 = kt + 1, kn2 = kt + 2;
    ldA(db, 0); ldB(db, 0);
    stgA(kn1, 0);
    __builtin_amdgcn_sched_barrier(0);
    __builtin_amdgcn_s_barrier();
    __builtin_amdgcn_s_setprio(1);
    MMQ(0, 0);
    __builtin_amdgcn_s_setprio(0);
    __builtin_amdgcn_s_barrier();
    ldA(db, 1);
    stgB(kn1, 1);
    __builtin_amdgcn_sched_barrier(0);
    __builtin_amdgcn_s_barrier();
    __builtin_amdgcn_s_setprio(1);
    MMQ(1, 0);
    __builtin_amdgcn_s_setprio(0);
    __builtin_amdgcn_s_barrier();
    ldB(db, 1);
    stgB(kn2, 0);
    __builtin_amdgcn_sched_barrier(0);
    __builtin_amdgcn_s_barrier();
    __builtin_amdgcn_s_setprio(1);
    MMQ(1, 1);
    __builtin_amdgcn_s_setprio(0);
    __builtin_amdgcn_s_barrier();
    ldA(db, 0);
    stgA(kn2, 1);
    __builtin_amdgcn_sched_barrier(0);
    asm volatile("s_waitcnt vmcnt(4)" ::: "memory");
    __builtin_amdgcn_s_barrier();
    __builtin_amdgcn_s_setprio(1);
    MMQ(0, 1);
    __builtin_amdgcn_s_setprio(0);
    __builtin_amdgcn_s_barrier();
  }

  float bv[2][2], wv[2][2];
#pragma unroll
  for (int qc = 0; qc < 2; ++qc)
#pragma unroll
    for (int j = 0; j < 2; ++j) {
      int c = colBase + qc * 128 + wq_c * 32 + j * 16 + l15;
      bv[qc][j] = bias[c];
      wv[qc][j] = W3[c];
    }
#pragma unroll
  for (int qr = 0; qr < 2; ++qr)
#pragma unroll
    for (int i = 0; i < 4; ++i)
#pragma unroll
      for (int q = 0; q < 4; ++q) {
        float s = 0.f;
#pragma unroll
        for (int qc = 0; qc < 2; ++qc)
#pragma unroll
          for (int j = 0; j < 2; ++j)
            s += fmaxf(acc[qr * 4 + i][qc * 2 + j][q] + bv[qc][j], 0.f) * wv[qc][j];
        s += __shfl_xor(s, 1); s += __shfl_xor(s, 2);
        s += __shfl_xor(s, 4); s += __shfl_xor(s, 8);
        if (l15 == 0)
          sRed[qr * 128 + wq_r * 64 + i * 16 + l16 * 4 + q][wq_c] = s;
      }
  __syncthreads();
  if (t < 256)
    atomicAdd(&scores[rowBase + t],
              sRed[t][0] + sRed[t][1] + sRed[t][2] + sRed[t][3]);
}

// ===========================================================================
// Shared 128x128 EPI-0 GEMM body (2-phase, gload_lds, slot-XOR swizzle)
// ===========================================================================
__device__ __forceinline__ void gemm_body(
    const _Float16* __restrict__ A, const _Float16* __restrict__ Bt,
    float* __restrict__ Cf, int N, int K, int rowBase, int colBase) {
  __shared__ __align__(16) _Float16 sA[8192];
  __shared__ __align__(16) _Float16 sB[8192];
  const int tid = threadIdx.x;
  const int lane = tid & 63;
  const int wave = tid >> 6;
  const int wr = wave >> 1, wc = wave & 1;
  const int l15 = lane & 15, l16 = lane >> 4;
  const int rsw = (l15 >> 1) & 3;
  const int sRow = tid >> 2;
  const int swz8 = (((tid & 3) ^ ((tid >> 3) & 3)) << 3);
  const _Float16* gA = A + (size_t)(rowBase + sRow) * K + swz8;
  const _Float16* gB = Bt + (size_t)(colBase + sRow) * K + swz8;
  _Float16* lA = sA + tid * 8;
  _Float16* lB = sB + tid * 8;

  floatx4 acc[4][4] = {};
  for (int k0 = 0; k0 < K; k0 += 64) {
    GLOAD16(gA + k0,               lA);
    GLOAD16(gA + 64 * K + k0,      lA + 2048);
    GLOAD16(gA + k0 + 32,          lA + 4096);
    GLOAD16(gA + 64 * K + k0 + 32, lA + 6144);
    GLOAD16(gB + k0,               lB);
    GLOAD16(gB + 64 * K + k0,      lB + 2048);
    GLOAD16(gB + k0 + 32,          lB + 4096);
    GLOAD16(gB + 64 * K + k0 + 32, lB + 6144);
    __syncthreads();
#pragma unroll
    for (int h = 0; h < 2; ++h) {
      const int hb = h * 4096;
      half8 aF[4], bF[4];
#pragma unroll
      for (int i = 0; i < 4; ++i)
        aF[i] = *(const half8*)&sA[hb + (wr * 64 + i * 16 + l15) * 32 + ((l16 ^ rsw) << 3)];
#pragma unroll
      for (int j = 0; j < 4; ++j)
        bF[j] = *(const half8*)&sB[hb + (wc * 64 + j * 16 + l15) * 32 + ((l16 ^ rsw) << 3)];
#pragma unroll
      for (int i = 0; i < 4; ++i)
#pragma unroll
        for (int j = 0; j < 4; ++j)
          acc[i][j] = __builtin_amdgcn_mfma_f32_16x16x32_f16(aF[i], bF[j], acc[i][j], 0, 0, 0);
    }
    __syncthreads();
  }
#pragma unroll
  for (int i = 0; i < 4; ++i)
#pragma unroll
    for (int q = 0; q < 4; ++q) {
      int r = rowBase + wr * 64 + i * 16 + l16 * 4 + q;
#pragma unroll
      for (int j = 0; j < 4; ++j) {
        int c = colBase + wc * 64 + j * 16 + l15;
        Cf[(size_t)r * N + c] = acc[i][j][q];
      }
    }
}

__global__ __launch_bounds__(256) void gemm_trio(
    const _Float16* __restrict__ textH, const _Float16* __restrict__ imgH,
    const _Float16* __restrict__ spanH, const _Float16* __restrict__ W1abT,
    float* __restrict__ dotTI, float* __restrict__ dotSI, float* __restrict__ AB1) {
  int bid = blockIdx.x;
  if (bid < 144)      gemm_body(textH, imgH, dotTI, 1152, D_, (bid / 9) * 128, (bid % 9) * 128);
  else if (bid < 252) { int b = bid - 144; gemm_body(spanH, imgH, dotSI, 1152, D_, (b / 9) * 128, (b % 9) * 128); }
  else                { int b = bid - 252; gemm_body(spanH, W1abT, AB1, 2048, D_, (b / 16) * 128, (b % 16) * 128); }
}

// ===========================================================================
// prep / small kernels
// ===========================================================================
__global__ __launch_bounds__(256) void cvt_all(
    const float* __restrict__ text, const float* __restrict__ span,
    const float* __restrict__ img, _Float16* __restrict__ textH,
    _Float16* __restrict__ spanH, _Float16* __restrict__ imgH) {
  long long i = (long long)blockIdx.x * 256 + threadIdx.x;
  const float* src; _Float16* dst; long long off;
  if (i < 262144)      { src = text; dst = textH; off = i; }
  else if (i < 458752) { src = span; dst = spanH; off = i - 262144; }
  else if (i < 606208) { src = img;  dst = imgH;  off = i - 458752; }
  else return;
  const float4* p = (const float4*)src + off * 2;
  float4 a = p[0], b = p[1];
  half8 h;
  h[0] = (_Float16)a.x; h[1] = (_Float16)a.y; h[2] = (_Float16)a.z; h[3] = (_Float16)a.w;
  h[4] = (_Float16)b.x; h[5] = (_Float16)b.y; h[6] = (_Float16)b.z; h[7] = (_Float16)b.w;
  *(half8*)(dst + off * 8) = h;
}

__global__ __launch_bounds__(256) void transpose_all(
    const float* __restrict__ W1, const float* __restrict__ W2,
    _Float16* __restrict__ W1abT, _Float16* __restrict__ W1cT,
    _Float16* __restrict__ W2T) {
  __shared__ float tbuf[32][33];
  const float* in; _Float16* out;
  switch (blockIdx.z) {
    case 0: in = W1;                 out = W1abT;                 break;
    case 1: in = W1 + 1024 * 1024;   out = W1abT + 1024 * 1024;   break;
    case 2: in = W1 + 2048 * 1024;   out = W1cT;                  break;
    default: in = W2;                out = W2T;                   break;
  }
  const int tx = threadIdx.x & 31, ty = threadIdx.x >> 5;
  const int k0 = blockIdx.y * 32, n0 = blockIdx.x * 32;
#pragma unroll
  for (int q = 0; q < 4; ++q)
    tbuf[ty + q * 8][tx] = in[(size_t)(k0 + ty + q * 8) * 1024 + n0 + tx];
  __syncthreads();
#pragma unroll
  for (int q = 0; q < 4; ++q)
    out[(size_t)(n0 + ty + q * 8) * 1024 + k0 + tx] = (_Float16)tbuf[tx][ty + q * 8];
}

__global__ __launch_bounds__(256) void idx_init(int* __restrict__ idxF, int* __restrict__ idxS) {
  int r = blockIdx.x * 256 + threadIdx.x;
  if (r >= ROWS) return;
  int bb = r / NPAIR, p = r - bb * NPAIR;
  int cum = 0, f = 0;
  while (true) { int cnt = NS - 1 - f; if (p < cum + cnt) break; cum += cnt; ++f; }
  idxF[r] = bb * NS + f;
  idxS[r] = bb * NS + f + 1 + (p - cum);
}

__global__ void init_scores(float* __restrict__ scores, const float* __restrict__ b3) {
  int idx = blockIdx.x * 256 + threadIdx.x;
  if (idx < ROWS) scores[idx] = b3[0];
}

__global__ __launch_bounds__(256) void extract_grounding(
    const float* __restrict__ dotSI, const float* __restrict__ smask,
    const float* __restrict__ imask, float* __restrict__ outg) {
  int idx = blockIdx.x * 256 + threadIdx.x;
  if (idx >= B_ * NS * LI) return;
  int b = idx / (NS * LI);
  int rem = idx - b * (NS * LI);
  int n = rem / LI, l = rem - n * LI;
  float v = dotSI[(size_t)(b * NS + n) * (B_ * LI) + b * LI + l];
  outg[idx] = (smask[b * NS + n] * imask[b * LI + l] != 0.f) ? v : NEGV;
}

__global__ __launch_bounds__(64) void sent_kernel(
    const float* __restrict__ dotTI, const float* __restrict__ tmask,
    const float* __restrict__ imask, float* __restrict__ S) {
  const int i = blockIdx.y, j = blockIdx.x, t = threadIdx.x;
  __shared__ float red1[64], red2[64];
  const int stride = B_ * LI;
  float e1 = 0.f;
  {
    float tm = tmask[i * NT + t];
    if (tm != 0.f) {
      const float* row = dotTI + (size_t)(i * NT + t) * stride + j * LI;
      float m = -INFINITY;
      for (int l = 0; l < LI; ++l) if (imask[j * LI + l] != 0.f) m = fmaxf(m, row[l]);
      float z = 0.f, w = 0.f;
      for (int l = 0; l < LI; ++l) if (imask[j * LI + l] != 0.f) {
        float d = row[l], p = expf(d - m);
        z += p; w += p * d;
      }
      e1 = w / z;
    }
  }
  red1[t] = e1;
  float e2 = 0.f;
  if (t < LI) {
    float im = imask[j * LI + t];
    if (im != 0.f) {
      const float* col = dotTI + (size_t)(i * NT) * stride + j * LI + t;
      float m = -INFINITY;
      for (int n = 0; n < NT; ++n) if (tmask[i * NT + n] != 0.f) m = fmaxf(m, col[(size_t)n * stride]);
      float z = 0.f, w = 0.f;
      for (int n = 0; n < NT; ++n) if (tmask[i * NT + n] != 0.f) {
        float d = col[(size_t)n * stride], p = expf(d - m);
        z += p; w += p * d;
      }
      e2 = w / z;
    }
  }
  red2[t] = e2;
  __syncthreads();
  if (t == 0) {
    float s1 = 0.f, s2 = 0.f, cn = 0.f, cl = 0.f;
    for (int n = 0; n < NT; ++n) { s1 += red1[n]; cn += tmask[i * NT + n]; }
    for (int l = 0; l < LI; ++l) { s2 += red2[l]; cl += imask[j * LI + l]; }
    S[i * B_ + j] = s1 / cn + s2 / cl;
  }
}

__global__ __launch_bounds__(64) void loss_kernel(
    const float* __restrict__ S, float* __restrict__ out) {
  __shared__ float sS[B_][B_ + 1];
  __shared__ float acc[B_];
  const int t = threadIdx.x;
  for (int e = t; e < B_ * B_; e += 64) sS[e / B_][e % B_] = S[e];
  __syncthreads();
  if (t < B_) {
    float m = -INFINITY;
    for (int j = 0; j < B_; ++j) m = fmaxf(m, sS[t][j]);
    float z = 0.f;
    for (int j = 0; j < B_; ++j) z += expf(sS[t][j] - m);
    float lr = m + logf(z);
    float m2 = -INFINITY;
    for (int i = 0; i < B_; ++i) m2 = fmaxf(m2, sS[i][t]);
    float z2 = 0.f;
    for (int i = 0; i < B_; ++i) z2 += expf(sS[i][t] - m2);
    float lc = m2 + logf(z2);
    acc[t] = 2.f * sS[t][t] - lr - lc;
  }
  __syncthreads();
  if (t == 0) {
    float s = 0.f;
    for (int i = 0; i < B_; ++i) s += acc[i];
    out[0] = -s / (float)B_;
  }
}

extern "C" void kernel_launch(void* const* d_in, const int* in_sizes, int n_in,
                              void* d_out, int out_size, void* d_ws, size_t ws_size,
                              hipStream_t stream) {
  const float* text  = (const float*)d_in[0];
  const float* span  = (const float*)d_in[1];
  const float* img   = (const float*)d_in[2];
  const float* tmask = (const float*)d_in[3];
  const float* smask = (const float*)d_in[4];
  const float* imask = (const float*)d_in[5];
  const float* W1    = (const float*)d_in[6];
  const float* b1    = (const float*)d_in[7];
  const float* W2    = (const float*)d_in[8];
  const float* b2    = (const float*)d_in[9];
  const float* W3    = (const float*)d_in[10];
  const float* b3    = (const float*)d_in[11];

  float* out     = (float*)d_out;
  float* outLoss = out;
  float* outG    = out + 1;
  float* outT    = out + 1 + (size_t)B_ * NS * LI;

  // ---- workspace layout ----
  char* w = (char*)d_ws;
  float*    dotTI = (float*)w;            w += (size_t)(B_*NT) * (B_*LI) * 4;
  float*    dotSI = (float*)w;            w += (size_t)(B_*NS) * (B_*LI) * 4;
  float*    S     = (float*)w;            w += 1024 * 4;
  float*    AB1   = (float*)w;            w += (size_t)1536 * 2048 * 4;
  _Float16* h1    = (_Float16*)w;         w += (size_t)ROWS * 1024 * 2;
  _Float16* textH = (_Float16*)w;         w += (size_t)2048 * 1024 * 2;
  _Float16* spanH = (_Float16*)w;         w += (size_t)1536 * 1024 * 2;
  _Float16* imgH  = (_Float16*)w;         w += (size_t)1152 * 1024 * 2;
  _Float16* W1abT = (_Float16*)w;         w += (size_t)2048 * 1024 * 2;
  _Float16* W1cT  = (_Float16*)w;         w += (size_t)1024 * 1024 * 2;
  _Float16* W2T   = (_Float16*)w;         w += (size_t)1024 * 1024 * 2;
  int*      idxF  = (int*)w;              w += ROWS * 4;
  int*      idxS  = (int*)w;              w += ROWS * 4;
  (void)ws_size; (void)in_sizes; (void)n_in; (void)out_size;

  // ---- prep ----
  cvt_all<<<(606208 + 255) / 256, 256, 0, stream>>>(text, span, img, textH, spanH, imgH);
  transpose_all<<<dim3(32, 32, 4), 256, 0, stream>>>(W1, W2, W1abT, W1cT, W2T);
  idx_init<<<(ROWS + 255) / 256, 256, 0, stream>>>(idxF, idxS);

  // ---- small GEMMs merged: dotTI, dotSI, AB1 ----
  gemm_trio<<<444, 256, 0, stream>>>(textH, imgH, spanH, W1abT, dotTI, dotSI, AB1);
  sent_kernel<<<dim3(B_, B_), 64, 0, stream>>>(dotTI, tmask, imask, S);
  loss_kernel<<<1, 64, 0, stream>>>(S, outLoss);
  extract_grounding<<<(B_*NS*LI + 255) / 256, 256, 0, stream>>>(dotSI, smask, imask, outG);

  // ---- pairwise MLP ----
  gemm1_8ph<<<564, 512, 0, stream>>>(spanH, W1cT, AB1, b1, h1, idxF, idxS);
  init_scores<<<(ROWS + 255) / 256, 256, 0, stream>>>(outT, b3);
  gemm2_8ph<<<564, 512, 0, stream>>>(h1, W2T, outT, b2, W3);
}

// Round 9
// 330.758 us; speedup vs baseline: 1.0582x; 1.0425x over previous
//
#include <hip/hip_runtime.h>
#include <math.h>
#include <stdint.h>

#define B_    32
#define NT    64
#define NS    48
#define LI    36
#define D_    1024
#define H_    1024
#define NPAIR 1128            // 48*47/2
#define ROWS  (B_*NPAIR)      // 36096 = 282*128 = 141*256
#define NEGV  -9.0e9f
#define NROWT 282             // 128-row tiles (gemm1)
#define CPX   36              // ceil(282/8) row tiles per XCD (gemm1 remap)

typedef _Float16 half8 __attribute__((ext_vector_type(8)));
typedef float floatx4 __attribute__((ext_vector_type(4)));
typedef __attribute__((address_space(3))) uint32_t lds_u32;
typedef __attribute__((address_space(1))) const uint32_t glb_u32;

#define GLOAD16(src, dst) __builtin_amdgcn_global_load_lds((glb_u32*)(src), (lds_u32*)(dst), 16, 0, 0)

#define MMQ(QR, QC)                                                            \
  {                                                                            \
    _Pragma("unroll") for (int i = 0; i < 4; ++i) {                            \
      _Pragma("unroll") for (int j = 0; j < 2; ++j) {                          \
        acc[QR * 4 + i][QC * 2 + j] = __builtin_amdgcn_mfma_f32_16x16x32_f16(  \
            aF[i][0], bF[j][0], acc[QR * 4 + i][QC * 2 + j], 0, 0, 0);         \
        acc[QR * 4 + i][QC * 2 + j] = __builtin_amdgcn_mfma_f32_16x16x32_f16(  \
            aF[i][1], bF[j][1], acc[QR * 4 + i][QC * 2 + j], 0, 0, 0);         \
      }                                                                        \
    }                                                                          \
  }

// ===========================================================================
// gemm2_8ph: scores[r] += sum_c relu((h1 @ W2T^T)[r,c] + b2[c]) * W3[c]
// 256x256, BK=64, 8 waves, 4 phases/K-tile.  WAIT FIX (R9): P3 vmcnt(6)
// (drains only the 3 oldest half-tiles, each >=3-phase flight ~900cy);
// B1(kt+1) drained by vmcnt(8) at P1(kt+1) (4.5-phase flight).  Never <3
// half-tiles in flight (m201's N=6 formula).
// ===========================================================================
__global__ __launch_bounds__(512, 2) void gemm2_8ph(
    const _Float16* __restrict__ Am, const _Float16* __restrict__ Bt,
    float* __restrict__ scores, const float* __restrict__ bias,
    const float* __restrict__ W3) {
  __shared__ __align__(16) _Float16 sP[65536];
  __shared__ float sRed[256][4];

  const int orig = blockIdx.x;               // 564 blocks, bijective remap
  const int xcd = orig & 7, pos = orig >> 3;
  const int wg = (xcd < 4 ? xcd * 71 : 284 + (xcd - 4) * 70) + pos;
  const int rowBase = (wg >> 2) * 256;
  const int colBase = (wg & 3) * 256;

  const int t = threadIdx.x;
  const int wave = t >> 6, lane = t & 63;
  const int wq_r = wave >> 2, wq_c = wave & 3;
  const int l15 = lane & 15, l16 = lane >> 4;
  const int sxor = l15 & 7;

  const int srow0 = t >> 3, srow1 = (512 + t) >> 3;
  const int lcol0 = ((t & 7) ^ (srow0 & 7)) << 3;
  const int lcol1 = (((512 + t) & 7) ^ (srow1 & 7)) << 3;
  const _Float16* aS0 = Am + (size_t)(rowBase + srow0) * D_ + lcol0;
  const _Float16* aS1 = Am + (size_t)(rowBase + srow1) * D_ + lcol1;
  const _Float16* bS0 = Bt + (size_t)(colBase + srow0) * D_ + lcol0;
  const _Float16* bS1 = Bt + (size_t)(colBase + srow1) * D_ + lcol1;

  auto stgA = [&](int kt, int h) {
    const int db = kt & 1;
    const size_t so = (size_t)(kt & 15) * 64 + (size_t)h * 128 * D_;
    _Float16* d = sP + ((db << 1) + h) * 8192;
    GLOAD16(aS0 + so, d + t * 8);
    GLOAD16(aS1 + so, d + 4096 + t * 8);
  };
  auto stgB = [&](int kt, int h) {
    const int db = kt & 1;
    const size_t so = (size_t)(kt & 15) * 64 + (size_t)h * 128 * D_;
    _Float16* d = sP + 32768 + ((db << 1) + h) * 8192;
    GLOAD16(bS0 + so, d + t * 8);
    GLOAD16(bS1 + so, d + 4096 + t * 8);
  };

  const int aRdRow = (wq_r * 64 + l15) * 64;
  const int bRdRow = (wq_c * 32 + l15) * 64;
  const int rdSlot0 = ((l16) ^ sxor) << 3;
  const int rdSlot1 = ((4 + l16) ^ sxor) << 3;

  half8 aF[4][2], bF[2][2];
  floatx4 acc[8][4] = {};

  auto ldA = [&](int db, int qr) {
    const _Float16* p = sP + ((db << 1) + qr) * 8192 + aRdRow;
#pragma unroll
    for (int i = 0; i < 4; ++i) {
      aF[i][0] = *(const half8*)(p + i * 1024 + rdSlot0);
      aF[i][1] = *(const half8*)(p + i * 1024 + rdSlot1);
    }
  };
  auto ldB = [&](int db, int qc) {
    const _Float16* p = sP + 32768 + ((db << 1) + qc) * 8192 + bRdRow;
#pragma unroll
    for (int j = 0; j < 2; ++j) {
      bF[j][0] = *(const half8*)(p + j * 1024 + rdSlot0);
      bF[j][1] = *(const half8*)(p + j * 1024 + rdSlot1);
    }
  };

  // prologue: stage K-tile 0 + first 2 halves of K-tile 1; drain kt0 only
  stgB(0, 0); stgA(0, 1); stgA(0, 0); stgB(0, 1); stgB(1, 0); stgA(1, 1);
  asm volatile("s_waitcnt vmcnt(4)" ::: "memory");
  __builtin_amdgcn_s_barrier();

#pragma unroll 1
  for (int kt = 0; kt < 16; ++kt) {
    const int db = kt & 1;
    const int kn1 = kt + 1, kn2 = kt + 2;
    // ---- P0: Q(0,0); stage A0(kt+1)
    ldA(db, 0); ldB(db, 0);
    stgA(kn1, 0);
    __builtin_amdgcn_sched_barrier(0);
    __builtin_amdgcn_s_barrier();
    __builtin_amdgcn_s_setprio(1);
    MMQ(0, 0);
    __builtin_amdgcn_s_setprio(0);
    __builtin_amdgcn_s_barrier();
    // ---- P1: Q(1,0) reuse B0; stage B1(kt+1); drain B1(kt) [4.5-ph flight]
    ldA(db, 1);
    stgB(kn1, 1);
    __builtin_amdgcn_sched_barrier(0);
    asm volatile("s_waitcnt vmcnt(8)" ::: "memory");
    __builtin_amdgcn_s_barrier();
    __builtin_amdgcn_s_setprio(1);
    MMQ(1, 0);
    __builtin_amdgcn_s_setprio(0);
    __builtin_amdgcn_s_barrier();
    // ---- P2: Q(1,1) reuse A1; stage B0(kt+2)
    ldB(db, 1);
    stgB(kn2, 0);
    __builtin_amdgcn_sched_barrier(0);
    __builtin_amdgcn_s_barrier();
    __builtin_amdgcn_s_setprio(1);
    MMQ(1, 1);
    __builtin_amdgcn_s_setprio(0);
    __builtin_amdgcn_s_barrier();
    // ---- P3: Q(0,1); stage A1(kt+2); drain 3 oldest halves (vmcnt=6)
    ldA(db, 0);
    stgA(kn2, 1);
    __builtin_amdgcn_sched_barrier(0);
    asm volatile("s_waitcnt vmcnt(6)" ::: "memory");
    __builtin_amdgcn_s_barrier();
    __builtin_amdgcn_s_setprio(1);
    MMQ(0, 1);
    __builtin_amdgcn_s_setprio(0);
    __builtin_amdgcn_s_barrier();
  }

  // ---- epilogue: s = sum_c relu(acc + b2)*W3, 16-lane reduce, atomicAdd
  float bv[2][2], wv[2][2];
#pragma unroll
  for (int qc = 0; qc < 2; ++qc)
#pragma unroll
    for (int j = 0; j < 2; ++j) {
      int c = colBase + qc * 128 + wq_c * 32 + j * 16 + l15;
      bv[qc][j] = bias[c];
      wv[qc][j] = W3[c];
    }
#pragma unroll
  for (int qr = 0; qr < 2; ++qr)
#pragma unroll
    for (int i = 0; i < 4; ++i)
#pragma unroll
      for (int q = 0; q < 4; ++q) {
        float s = 0.f;
#pragma unroll
        for (int qc = 0; qc < 2; ++qc)
#pragma unroll
          for (int j = 0; j < 2; ++j)
            s += fmaxf(acc[qr * 4 + i][qc * 2 + j][q] + bv[qc][j], 0.f) * wv[qc][j];
        s += __shfl_xor(s, 1); s += __shfl_xor(s, 2);
        s += __shfl_xor(s, 4); s += __shfl_xor(s, 8);
        if (l15 == 0)
          sRed[qr * 128 + wq_r * 64 + i * 16 + l16 * 4 + q][wq_c] = s;
      }
  __syncthreads();
  if (t < 256)
    atomicAdd(&scores[rowBase + t],
              sRed[t][0] + sRed[t][1] + sRed[t][2] + sRed[t][3]);
}

// ===========================================================================
// gemm1_fused (R6 2-phase, 140 us verified): h1 = relu((F.*S)@W1c + A1+B1+b1)
// ===========================================================================
__global__ __launch_bounds__(256) void gemm1_fused(
    const _Float16* __restrict__ spanH, const _Float16* __restrict__ W1cT,
    const float* __restrict__ AB1, const float* __restrict__ b1,
    _Float16* __restrict__ h1out,
    const int* __restrict__ idxF, const int* __restrict__ idxS) {
  __shared__ __align__(16) _Float16 sF[8192];
  __shared__ __align__(16) _Float16 sS[8192];
  __shared__ __align__(16) _Float16 sB[8192];
  __shared__ int sIF[128], sIS[128];
  int bid = blockIdx.x;
  int x = bid & 7, ord = bid >> 3;
  int rowT = x * CPX + (ord >> 3);
  int colT = ord & 7;
  if (rowT >= NROWT) return;
  const int rowBase = rowT * 128, colBase = colT * 128;
  const int tid = threadIdx.x;
  const int lane = tid & 63;
  const int wave = tid >> 6;
  const int wr = wave >> 1, wc = wave & 1;
  const int l15 = lane & 15, l16 = lane >> 4;
  const int rsw = (l15 >> 1) & 3;

  if (tid < 128) {
    int rg = rowBase + tid;
    sIF[tid] = idxF[rg];
    sIS[tid] = idxS[rg];
  }
  __syncthreads();

  const int sRow = tid >> 2;
  const int swz8 = (((tid & 3) ^ ((tid >> 3) & 3)) << 3);
  const _Float16* gF0 = spanH + (size_t)sIF[sRow] * D_ + swz8;
  const _Float16* gF1 = spanH + (size_t)sIF[sRow + 64] * D_ + swz8;
  const _Float16* gS0 = spanH + (size_t)sIS[sRow] * D_ + swz8;
  const _Float16* gS1 = spanH + (size_t)sIS[sRow + 64] * D_ + swz8;
  const _Float16* gB  = W1cT + (size_t)(colBase + sRow) * D_ + swz8;
  _Float16* lF = sF + tid * 8;
  _Float16* lS = sS + tid * 8;
  _Float16* lB = sB + tid * 8;

  floatx4 acc[4][4] = {};
  for (int k0 = 0; k0 < D_; k0 += 64) {
    GLOAD16(gF0 + k0,      lF);
    GLOAD16(gF1 + k0,      lF + 2048);
    GLOAD16(gF0 + k0 + 32, lF + 4096);
    GLOAD16(gF1 + k0 + 32, lF + 6144);
    GLOAD16(gS0 + k0,      lS);
    GLOAD16(gS1 + k0,      lS + 2048);
    GLOAD16(gS0 + k0 + 32, lS + 4096);
    GLOAD16(gS1 + k0 + 32, lS + 6144);
    GLOAD16(gB + k0,               lB);
    GLOAD16(gB + 64 * D_ + k0,     lB + 2048);
    GLOAD16(gB + k0 + 32,          lB + 4096);
    GLOAD16(gB + 64 * D_ + k0 + 32,lB + 6144);
    __syncthreads();
#pragma unroll
    for (int h = 0; h < 2; ++h) {
      const int hb = h * 4096;
      half8 aF[4], bF[4];
#pragma unroll
      for (int i = 0; i < 4; ++i) {
        int off = hb + (wr * 64 + i * 16 + l15) * 32 + ((l16 ^ rsw) << 3);
        half8 f = *(const half8*)&sF[off];
        half8 s = *(const half8*)&sS[off];
        aF[i] = f * s;
      }
#pragma unroll
      for (int j = 0; j < 4; ++j)
        bF[j] = *(const half8*)&sB[hb + (wc * 64 + j * 16 + l15) * 32 + ((l16 ^ rsw) << 3)];
#pragma unroll
      for (int i = 0; i < 4; ++i)
#pragma unroll
        for (int j = 0; j < 4; ++j)
          acc[i][j] = __builtin_amdgcn_mfma_f32_16x16x32_f16(aF[i], bF[j], acc[i][j], 0, 0, 0);
    }
    __syncthreads();
  }

  int cols[4]; float bv[4];
#pragma unroll
  for (int j = 0; j < 4; ++j) {
    cols[j] = colBase + wc * 64 + j * 16 + l15;
    bv[j] = b1[cols[j]];
  }
#pragma unroll
  for (int i = 0; i < 4; ++i)
#pragma unroll
    for (int q = 0; q < 4; ++q) {
      int rL = wr * 64 + i * 16 + l16 * 4 + q;
      int rG = rowBase + rL;
      const float* ap = AB1 + (size_t)sIF[rL] * 2048;
      const float* bp = AB1 + (size_t)sIS[rL] * 2048 + 1024;
#pragma unroll
      for (int j = 0; j < 4; ++j) {
        int c = cols[j];
        float v = acc[i][j][q] + ap[c] + bp[c] + bv[j];
        h1out[(size_t)rG * 1024 + c] = (_Float16)fmaxf(v, 0.f);
      }
    }
}

// ===========================================================================
// Shared 128x128 EPI-0 GEMM body (2-phase, gload_lds, slot-XOR swizzle)
// ===========================================================================
__device__ __forceinline__ void gemm_body(
    const _Float16* __restrict__ A, const _Float16* __restrict__ Bt,
    float* __restrict__ Cf, int N, int K, int rowBase, int colBase) {
  __shared__ __align__(16) _Float16 sA[8192];
  __shared__ __align__(16) _Float16 sB[8192];
  const int tid = threadIdx.x;
  const int lane = tid & 63;
  const int wave = tid >> 6;
  const int wr = wave >> 1, wc = wave & 1;
  const int l15 = lane & 15, l16 = lane >> 4;
  const int rsw = (l15 >> 1) & 3;
  const int sRow = tid >> 2;
  const int swz8 = (((tid & 3) ^ ((tid >> 3) & 3)) << 3);
  const _Float16* gA = A + (size_t)(rowBase + sRow) * K + swz8;
  const _Float16* gB = Bt + (size_t)(colBase + sRow) * K + swz8;
  _Float16* lA = sA + tid * 8;
  _Float16* lB = sB + tid * 8;

  floatx4 acc[4][4] = {};
  for (int k0 = 0; k0 < K; k0 += 64) {
    GLOAD16(gA + k0,               lA);
    GLOAD16(gA + 64 * K + k0,      lA + 2048);
    GLOAD16(gA + k0 + 32,          lA + 4096);
    GLOAD16(gA + 64 * K + k0 + 32, lA + 6144);
    GLOAD16(gB + k0,               lB);
    GLOAD16(gB + 64 * K + k0,      lB + 2048);
    GLOAD16(gB + k0 + 32,          lB + 4096);
    GLOAD16(gB + 64 * K + k0 + 32, lB + 6144);
    __syncthreads();
#pragma unroll
    for (int h = 0; h < 2; ++h) {
      const int hb = h * 4096;
      half8 aF[4], bF[4];
#pragma unroll
      for (int i = 0; i < 4; ++i)
        aF[i] = *(const half8*)&sA[hb + (wr * 64 + i * 16 + l15) * 32 + ((l16 ^ rsw) << 3)];
#pragma unroll
      for (int j = 0; j < 4; ++j)
        bF[j] = *(const half8*)&sB[hb + (wc * 64 + j * 16 + l15) * 32 + ((l16 ^ rsw) << 3)];
#pragma unroll
      for (int i = 0; i < 4; ++i)
#pragma unroll
        for (int j = 0; j < 4; ++j)
          acc[i][j] = __builtin_amdgcn_mfma_f32_16x16x32_f16(aF[i], bF[j], acc[i][j], 0, 0, 0);
    }
    __syncthreads();
  }
#pragma unroll
  for (int i = 0; i < 4; ++i)
#pragma unroll
    for (int q = 0; q < 4; ++q) {
      int r = rowBase + wr * 64 + i * 16 + l16 * 4 + q;
#pragma unroll
      for (int j = 0; j < 4; ++j) {
        int c = colBase + wc * 64 + j * 16 + l15;
        Cf[(size_t)r * N + c] = acc[i][j][q];
      }
    }
}

__global__ __launch_bounds__(256) void gemm_trio(
    const _Float16* __restrict__ textH, const _Float16* __restrict__ imgH,
    const _Float16* __restrict__ spanH, const _Float16* __restrict__ W1abT,
    float* __restrict__ dotTI, float* __restrict__ dotSI, float* __restrict__ AB1) {
  int bid = blockIdx.x;
  if (bid < 144)      gemm_body(textH, imgH, dotTI, 1152, D_, (bid / 9) * 128, (bid % 9) * 128);
  else if (bid < 252) { int b = bid - 144; gemm_body(spanH, imgH, dotSI, 1152, D_, (b / 9) * 128, (b % 9) * 128); }
  else                { int b = bid - 252; gemm_body(spanH, W1abT, AB1, 2048, D_, (b / 16) * 128, (b % 16) * 128); }
}

// ===========================================================================
// prep / small kernels
// ===========================================================================
__global__ __launch_bounds__(256) void cvt_all(
    const float* __restrict__ text, const float* __restrict__ span,
    const float* __restrict__ img, _Float16* __restrict__ textH,
    _Float16* __restrict__ spanH, _Float16* __restrict__ imgH) {
  long long i = (long long)blockIdx.x * 256 + threadIdx.x;
  const float* src; _Float16* dst; long long off;
  if (i < 262144)      { src = text; dst = textH; off = i; }
  else if (i < 458752) { src = span; dst = spanH; off = i - 262144; }
  else if (i < 606208) { src = img;  dst = imgH;  off = i - 458752; }
  else return;
  const float4* p = (const float4*)src + off * 2;
  float4 a = p[0], b = p[1];
  half8 h;
  h[0] = (_Float16)a.x; h[1] = (_Float16)a.y; h[2] = (_Float16)a.z; h[3] = (_Float16)a.w;
  h[4] = (_Float16)b.x; h[5] = (_Float16)b.y; h[6] = (_Float16)b.z; h[7] = (_Float16)b.w;
  *(half8*)(dst + off * 8) = h;
}

__global__ __launch_bounds__(256) void transpose_all(
    const float* __restrict__ W1, const float* __restrict__ W2,
    _Float16* __restrict__ W1abT, _Float16* __restrict__ W1cT,
    _Float16* __restrict__ W2T) {
  __shared__ float tbuf[32][33];
  const float* in; _Float16* out;
  switch (blockIdx.z) {
    case 0: in = W1;                 out = W1abT;                 break;
    case 1: in = W1 + 1024 * 1024;   out = W1abT + 1024 * 1024;   break;
    case 2: in = W1 + 2048 * 1024;   out = W1cT;                  break;
    default: in = W2;                out = W2T;                   break;
  }
  const int tx = threadIdx.x & 31, ty = threadIdx.x >> 5;
  const int k0 = blockIdx.y * 32, n0 = blockIdx.x * 32;
#pragma unroll
  for (int q = 0; q < 4; ++q)
    tbuf[ty + q * 8][tx] = in[(size_t)(k0 + ty + q * 8) * 1024 + n0 + tx];
  __syncthreads();
#pragma unroll
  for (int q = 0; q < 4; ++q)
    out[(size_t)(n0 + ty + q * 8) * 1024 + k0 + tx] = (_Float16)tbuf[tx][ty + q * 8];
}

__global__ __launch_bounds__(256) void idx_init(int* __restrict__ idxF, int* __restrict__ idxS) {
  int r = blockIdx.x * 256 + threadIdx.x;
  if (r >= ROWS) return;
  int bb = r / NPAIR, p = r - bb * NPAIR;
  int cum = 0, f = 0;
  while (true) { int cnt = NS - 1 - f; if (p < cum + cnt) break; cum += cnt; ++f; }
  idxF[r] = bb * NS + f;
  idxS[r] = bb * NS + f + 1 + (p - cum);
}

__global__ void init_scores(float* __restrict__ scores, const float* __restrict__ b3) {
  int idx = blockIdx.x * 256 + threadIdx.x;
  if (idx < ROWS) scores[idx] = b3[0];
}

__global__ __launch_bounds__(256) void extract_grounding(
    const float* __restrict__ dotSI, const float* __restrict__ smask,
    const float* __restrict__ imask, float* __restrict__ outg) {
  int idx = blockIdx.x * 256 + threadIdx.x;
  if (idx >= B_ * NS * LI) return;
  int b = idx / (NS * LI);
  int rem = idx - b * (NS * LI);
  int n = rem / LI, l = rem - n * LI;
  float v = dotSI[(size_t)(b * NS + n) * (B_ * LI) + b * LI + l];
  outg[idx] = (smask[b * NS + n] * imask[b * LI + l] != 0.f) ? v : NEGV;
}

__global__ __launch_bounds__(64) void sent_kernel(
    const float* __restrict__ dotTI, const float* __restrict__ tmask,
    const float* __restrict__ imask, float* __restrict__ S) {
  const int i = blockIdx.y, j = blockIdx.x, t = threadIdx.x;
  __shared__ float red1[64], red2[64];
  const int stride = B_ * LI;
  float e1 = 0.f;
  {
    float tm = tmask[i * NT + t];
    if (tm != 0.f) {
      const float* row = dotTI + (size_t)(i * NT + t) * stride + j * LI;
      float m = -INFINITY;
      for (int l = 0; l < LI; ++l) if (imask[j * LI + l] != 0.f) m = fmaxf(m, row[l]);
      float z = 0.f, w = 0.f;
      for (int l = 0; l < LI; ++l) if (imask[j * LI + l] != 0.f) {
        float d = row[l], p = expf(d - m);
        z += p; w += p * d;
      }
      e1 = w / z;
    }
  }
  red1[t] = e1;
  float e2 = 0.f;
  if (t < LI) {
    float im = imask[j * LI + t];
    if (im != 0.f) {
      const float* col = dotTI + (size_t)(i * NT) * stride + j * LI + t;
      float m = -INFINITY;
      for (int n = 0; n < NT; ++n) if (tmask[i * NT + n] != 0.f) m = fmaxf(m, col[(size_t)n * stride]);
      float z = 0.f, w = 0.f;
      for (int n = 0; n < NT; ++n) if (tmask[i * NT + n] != 0.f) {
        float d = col[(size_t)n * stride], p = expf(d - m);
        z += p; w += p * d;
      }
      e2 = w / z;
    }
  }
  red2[t] = e2;
  __syncthreads();
  if (t == 0) {
    float s1 = 0.f, s2 = 0.f, cn = 0.f, cl = 0.f;
    for (int n = 0; n < NT; ++n) { s1 += red1[n]; cn += tmask[i * NT + n]; }
    for (int l = 0; l < LI; ++l) { s2 += red2[l]; cl += imask[j * LI + l]; }
    S[i * B_ + j] = s1 / cn + s2 / cl;
  }
}

__global__ __launch_bounds__(64) void loss_kernel(
    const float* __restrict__ S, float* __restrict__ out) {
  __shared__ float sS[B_][B_ + 1];
  __shared__ float acc[B_];
  const int t = threadIdx.x;
  for (int e = t; e < B_ * B_; e += 64) sS[e / B_][e % B_] = S[e];
  __syncthreads();
  if (t < B_) {
    float m = -INFINITY;
    for (int j = 0; j < B_; ++j) m = fmaxf(m, sS[t][j]);
    float z = 0.f;
    for (int j = 0; j < B_; ++j) z += expf(sS[t][j] - m);
    float lr = m + logf(z);
    float m2 = -INFINITY;
    for (int i = 0; i < B_; ++i) m2 = fmaxf(m2, sS[i][t]);
    float z2 = 0.f;
    for (int i = 0; i < B_; ++i) z2 += expf(sS[i][t] - m2);
    float lc = m2 + logf(z2);
    acc[t] = 2.f * sS[t][t] - lr - lc;
  }
  __syncthreads();
  if (t == 0) {
    float s = 0.f;
    for (int i = 0; i < B_; ++i) s += acc[i];
    out[0] = -s / (float)B_;
  }
}

extern "C" void kernel_launch(void* const* d_in, const int* in_sizes, int n_in,
                              void* d_out, int out_size, void* d_ws, size_t ws_size,
                              hipStream_t stream) {
  const float* text  = (const float*)d_in[0];
  const float* span  = (const float*)d_in[1];
  const float* img   = (const float*)d_in[2];
  const float* tmask = (const float*)d_in[3];
  const float* smask = (const float*)d_in[4];
  const float* imask = (const float*)d_in[5];
  const float* W1    = (const float*)d_in[6];
  const float* b1    = (const float*)d_in[7];
  const float* W2    = (const float*)d_in[8];
  const float* b2    = (const float*)d_in[9];
  const float* W3    = (const float*)d_in[10];
  const float* b3    = (const float*)d_in[11];

  float* out     = (float*)d_out;
  float* outLoss = out;
  float* outG    = out + 1;
  float* outT    = out + 1 + (size_t)B_ * NS * LI;

  // ---- workspace layout ----
  char* w = (char*)d_ws;
  float*    dotTI = (float*)w;            w += (size_t)(B_*NT) * (B_*LI) * 4;
  float*    dotSI = (float*)w;            w += (size_t)(B_*NS) * (B_*LI) * 4;
  float*    S     = (float*)w;            w += 1024 * 4;
  float*    AB1   = (float*)w;            w += (size_t)1536 * 2048 * 4;
  _Float16* h1    = (_Float16*)w;         w += (size_t)ROWS * 1024 * 2;
  _Float16* textH = (_Float16*)w;         w += (size_t)2048 * 1024 * 2;
  _Float16* spanH = (_Float16*)w;         w += (size_t)1536 * 1024 * 2;
  _Float16* imgH  = (_Float16*)w;         w += (size_t)1152 * 1024 * 2;
  _Float16* W1abT = (_Float16*)w;         w += (size_t)2048 * 1024 * 2;
  _Float16* W1cT  = (_Float16*)w;         w += (size_t)1024 * 1024 * 2;
  _Float16* W2T   = (_Float16*)w;         w += (size_t)1024 * 1024 * 2;
  int*      idxF  = (int*)w;              w += ROWS * 4;
  int*      idxS  = (int*)w;              w += ROWS * 4;
  (void)ws_size; (void)in_sizes; (void)n_in; (void)out_size;

  // ---- prep ----
  cvt_all<<<(606208 + 255) / 256, 256, 0, stream>>>(text, span, img, textH, spanH, imgH);
  transpose_all<<<dim3(32, 32, 4), 256, 0, stream>>>(W1, W2, W1abT, W1cT, W2T);
  idx_init<<<(ROWS + 255) / 256, 256, 0, stream>>>(idxF, idxS);

  // ---- small GEMMs merged: dotTI, dotSI, AB1 ----
  gemm_trio<<<444, 256, 0, stream>>>(textH, imgH, spanH, W1abT, dotTI, dotSI, AB1);
  sent_kernel<<<dim3(B_, B_), 64, 0, stream>>>(dotTI, tmask, imask, S);
  loss_kernel<<<1, 64, 0, stream>>>(S, outLoss);
  extract_grounding<<<(B_*NS*LI + 255) / 256, 256, 0, stream>>>(dotSI, smask, imask, outG);

  // ---- pairwise MLP ----
  gemm1_fused<<<8 * CPX * 8, 256, 0, stream>>>(spanH, W1cT, AB1, b1, h1, idxF, idxS);
  init_scores<<<(ROWS + 255) / 256, 256, 0, stream>>>(outT, b3);
  gemm2_8ph<<<564, 512, 0, stream>>>(h1, W2T, outT, b2, W3);
}

// Round 10
// 328.521 us; speedup vs baseline: 1.0654x; 1.0068x over previous
//
#include <hip/hip_runtime.h>
#include <math.h>
#include <stdint.h>

#define B_    32
#define NT    64
#define NS    48
#define LI    36
#define D_    1024
#define H_    1024
#define NPAIR 1128            // 48*47/2
#define ROWS  (B_*NPAIR)      // 36096 = 282*128 = 141*256
#define NEGV  -9.0e9f
#define NROWT 282             // 128-row tiles (gemm1)
#define CPX   36              // ceil(282/8) row tiles per XCD (gemm1 remap)

typedef _Float16 half8 __attribute__((ext_vector_type(8)));
typedef float floatx4 __attribute__((ext_vector_type(4)));
typedef __attribute__((address_space(3))) uint32_t lds_u32;
typedef __attribute__((address_space(1))) const uint32_t glb_u32;

#define GLOAD16(src, dst) __builtin_amdgcn_global_load_lds((glb_u32*)(src), (lds_u32*)(dst), 16, 0, 0)

#define MMQ(QR, QC)                                                            \
  {                                                                            \
    _Pragma("unroll") for (int i = 0; i < 4; ++i) {                            \
      _Pragma("unroll") for (int j = 0; j < 2; ++j) {                          \
        acc[QR * 4 + i][QC * 2 + j] = __builtin_amdgcn_mfma_f32_16x16x32_f16(  \
            aF[i][0], bF[j][0], acc[QR * 4 + i][QC * 2 + j], 0, 0, 0);         \
        acc[QR * 4 + i][QC * 2 + j] = __builtin_amdgcn_mfma_f32_16x16x32_f16(  \
            aF[i][1], bF[j][1], acc[QR * 4 + i][QC * 2 + j], 0, 0, 0);         \
      }                                                                        \
    }                                                                          \
  }

// ===========================================================================
// gemm2_8ph (R9-validated): scores[r] += sum_c relu((h1@W2T^T)[r,c]+b2[c])*W3[c]
// + R10: col-tile-0 blocks add b3 (init_scores kernel removed; memset zeroes)
// ===========================================================================
__global__ __launch_bounds__(512, 2) void gemm2_8ph(
    const _Float16* __restrict__ Am, const _Float16* __restrict__ Bt,
    float* __restrict__ scores, const float* __restrict__ bias,
    const float* __restrict__ W3, const float* __restrict__ b3) {
  __shared__ __align__(16) _Float16 sP[65536];
  __shared__ float sRed[256][4];

  const int orig = blockIdx.x;               // 564 blocks, bijective remap
  const int xcd = orig & 7, pos = orig >> 3;
  const int wg = (xcd < 4 ? xcd * 71 : 284 + (xcd - 4) * 70) + pos;
  const int rowBase = (wg >> 2) * 256;
  const int colBase = (wg & 3) * 256;

  const int t = threadIdx.x;
  const int wave = t >> 6, lane = t & 63;
  const int wq_r = wave >> 2, wq_c = wave & 3;
  const int l15 = lane & 15, l16 = lane >> 4;
  const int sxor = l15 & 7;

  const int srow0 = t >> 3, srow1 = (512 + t) >> 3;
  const int lcol0 = ((t & 7) ^ (srow0 & 7)) << 3;
  const int lcol1 = (((512 + t) & 7) ^ (srow1 & 7)) << 3;
  const _Float16* aS0 = Am + (size_t)(rowBase + srow0) * D_ + lcol0;
  const _Float16* aS1 = Am + (size_t)(rowBase + srow1) * D_ + lcol1;
  const _Float16* bS0 = Bt + (size_t)(colBase + srow0) * D_ + lcol0;
  const _Float16* bS1 = Bt + (size_t)(colBase + srow1) * D_ + lcol1;

  auto stgA = [&](int kt, int h) {
    const int db = kt & 1;
    const size_t so = (size_t)(kt & 15) * 64 + (size_t)h * 128 * D_;
    _Float16* d = sP + ((db << 1) + h) * 8192;
    GLOAD16(aS0 + so, d + t * 8);
    GLOAD16(aS1 + so, d + 4096 + t * 8);
  };
  auto stgB = [&](int kt, int h) {
    const int db = kt & 1;
    const size_t so = (size_t)(kt & 15) * 64 + (size_t)h * 128 * D_;
    _Float16* d = sP + 32768 + ((db << 1) + h) * 8192;
    GLOAD16(bS0 + so, d + t * 8);
    GLOAD16(bS1 + so, d + 4096 + t * 8);
  };

  const int aRdRow = (wq_r * 64 + l15) * 64;
  const int bRdRow = (wq_c * 32 + l15) * 64;
  const int rdSlot0 = ((l16) ^ sxor) << 3;
  const int rdSlot1 = ((4 + l16) ^ sxor) << 3;

  half8 aF[4][2], bF[2][2];
  floatx4 acc[8][4] = {};

  auto ldA = [&](int db, int qr) {
    const _Float16* p = sP + ((db << 1) + qr) * 8192 + aRdRow;
#pragma unroll
    for (int i = 0; i < 4; ++i) {
      aF[i][0] = *(const half8*)(p + i * 1024 + rdSlot0);
      aF[i][1] = *(const half8*)(p + i * 1024 + rdSlot1);
    }
  };
  auto ldB = [&](int db, int qc) {
    const _Float16* p = sP + 32768 + ((db << 1) + qc) * 8192 + bRdRow;
#pragma unroll
    for (int j = 0; j < 2; ++j) {
      bF[j][0] = *(const half8*)(p + j * 1024 + rdSlot0);
      bF[j][1] = *(const half8*)(p + j * 1024 + rdSlot1);
    }
  };

  stgB(0, 0); stgA(0, 1); stgA(0, 0); stgB(0, 1); stgB(1, 0); stgA(1, 1);
  asm volatile("s_waitcnt vmcnt(4)" ::: "memory");
  __builtin_amdgcn_s_barrier();

#pragma unroll 1
  for (int kt = 0; kt < 16; ++kt) {
    const int db = kt & 1;
    const int kn1 = kt + 1, kn2 = kt + 2;
    ldA(db, 0); ldB(db, 0);
    stgA(kn1, 0);
    __builtin_amdgcn_sched_barrier(0);
    __builtin_amdgcn_s_barrier();
    __builtin_amdgcn_s_setprio(1);
    MMQ(0, 0);
    __builtin_amdgcn_s_setprio(0);
    __builtin_amdgcn_s_barrier();
    ldA(db, 1);
    stgB(kn1, 1);
    __builtin_amdgcn_sched_barrier(0);
    asm volatile("s_waitcnt vmcnt(8)" ::: "memory");
    __builtin_amdgcn_s_barrier();
    __builtin_amdgcn_s_setprio(1);
    MMQ(1, 0);
    __builtin_amdgcn_s_setprio(0);
    __builtin_amdgcn_s_barrier();
    ldB(db, 1);
    stgB(kn2, 0);
    __builtin_amdgcn_sched_barrier(0);
    __builtin_amdgcn_s_barrier();
    __builtin_amdgcn_s_setprio(1);
    MMQ(1, 1);
    __builtin_amdgcn_s_setprio(0);
    __builtin_amdgcn_s_barrier();
    ldA(db, 0);
    stgA(kn2, 1);
    __builtin_amdgcn_sched_barrier(0);
    asm volatile("s_waitcnt vmcnt(6)" ::: "memory");
    __builtin_amdgcn_s_barrier();
    __builtin_amdgcn_s_setprio(1);
    MMQ(0, 1);
    __builtin_amdgcn_s_setprio(0);
    __builtin_amdgcn_s_barrier();
  }

  float bv[2][2], wv[2][2];
#pragma unroll
  for (int qc = 0; qc < 2; ++qc)
#pragma unroll
    for (int j = 0; j < 2; ++j) {
      int c = colBase + qc * 128 + wq_c * 32 + j * 16 + l15;
      bv[qc][j] = bias[c];
      wv[qc][j] = W3[c];
    }
#pragma unroll
  for (int qr = 0; qr < 2; ++qr)
#pragma unroll
    for (int i = 0; i < 4; ++i)
#pragma unroll
      for (int q = 0; q < 4; ++q) {
        float s = 0.f;
#pragma unroll
        for (int qc = 0; qc < 2; ++qc)
#pragma unroll
          for (int j = 0; j < 2; ++j)
            s += fmaxf(acc[qr * 4 + i][qc * 2 + j][q] + bv[qc][j], 0.f) * wv[qc][j];
        s += __shfl_xor(s, 1); s += __shfl_xor(s, 2);
        s += __shfl_xor(s, 4); s += __shfl_xor(s, 8);
        if (l15 == 0)
          sRed[qr * 128 + wq_r * 64 + i * 16 + l16 * 4 + q][wq_c] = s;
      }
  __syncthreads();
  if (t < 256) {
    float s = sRed[t][0] + sRed[t][1] + sRed[t][2] + sRed[t][3];
    if ((wg & 3) == 0) s += b3[0];
    atomicAdd(&scores[rowBase + t], s);
  }
}

// ===========================================================================
// gemm1_fused (R6/R9 2-phase, 140us verified) + R10: inline pair-index calc
// ===========================================================================
__global__ __launch_bounds__(256) void gemm1_fused(
    const _Float16* __restrict__ spanH, const _Float16* __restrict__ W1cT,
    const float* __restrict__ AB1, const float* __restrict__ b1,
    _Float16* __restrict__ h1out) {
  __shared__ __align__(16) _Float16 sF[8192];
  __shared__ __align__(16) _Float16 sS[8192];
  __shared__ __align__(16) _Float16 sB[8192];
  __shared__ int sIF[128], sIS[128];
  int bid = blockIdx.x;
  int x = bid & 7, ord = bid >> 3;
  int rowT = x * CPX + (ord >> 3);
  int colT = ord & 7;
  if (rowT >= NROWT) return;
  const int rowBase = rowT * 128, colBase = colT * 128;
  const int tid = threadIdx.x;
  const int lane = tid & 63;
  const int wave = tid >> 6;
  const int wr = wave >> 1, wc = wave & 1;
  const int l15 = lane & 15, l16 = lane >> 4;
  const int rsw = (l15 >> 1) & 3;

  if (tid < 128) {
    int r = rowBase + tid;
    int bb = r / NPAIR;
    int p = r - bb * NPAIR;
    int cum = 0, f = 0;
    while (true) { int cnt = NS - 1 - f; if (p < cum + cnt) break; cum += cnt; ++f; }
    sIF[tid] = bb * NS + f;
    sIS[tid] = bb * NS + f + 1 + (p - cum);
  }
  __syncthreads();

  const int sRow = tid >> 2;
  const int swz8 = (((tid & 3) ^ ((tid >> 3) & 3)) << 3);
  const _Float16* gF0 = spanH + (size_t)sIF[sRow] * D_ + swz8;
  const _Float16* gF1 = spanH + (size_t)sIF[sRow + 64] * D_ + swz8;
  const _Float16* gS0 = spanH + (size_t)sIS[sRow] * D_ + swz8;
  const _Float16* gS1 = spanH + (size_t)sIS[sRow + 64] * D_ + swz8;
  const _Float16* gB  = W1cT + (size_t)(colBase + sRow) * D_ + swz8;
  _Float16* lF = sF + tid * 8;
  _Float16* lS = sS + tid * 8;
  _Float16* lB = sB + tid * 8;

  floatx4 acc[4][4] = {};
  for (int k0 = 0; k0 < D_; k0 += 64) {
    GLOAD16(gF0 + k0,      lF);
    GLOAD16(gF1 + k0,      lF + 2048);
    GLOAD16(gF0 + k0 + 32, lF + 4096);
    GLOAD16(gF1 + k0 + 32, lF + 6144);
    GLOAD16(gS0 + k0,      lS);
    GLOAD16(gS1 + k0,      lS + 2048);
    GLOAD16(gS0 + k0 + 32, lS + 4096);
    GLOAD16(gS1 + k0 + 32, lS + 6144);
    GLOAD16(gB + k0,               lB);
    GLOAD16(gB + 64 * D_ + k0,     lB + 2048);
    GLOAD16(gB + k0 + 32,          lB + 4096);
    GLOAD16(gB + 64 * D_ + k0 + 32,lB + 6144);
    __syncthreads();
#pragma unroll
    for (int h = 0; h < 2; ++h) {
      const int hb = h * 4096;
      half8 aF[4], bF[4];
#pragma unroll
      for (int i = 0; i < 4; ++i) {
        int off = hb + (wr * 64 + i * 16 + l15) * 32 + ((l16 ^ rsw) << 3);
        half8 f = *(const half8*)&sF[off];
        half8 s = *(const half8*)&sS[off];
        aF[i] = f * s;
      }
#pragma unroll
      for (int j = 0; j < 4; ++j)
        bF[j] = *(const half8*)&sB[hb + (wc * 64 + j * 16 + l15) * 32 + ((l16 ^ rsw) << 3)];
#pragma unroll
      for (int i = 0; i < 4; ++i)
#pragma unroll
        for (int j = 0; j < 4; ++j)
          acc[i][j] = __builtin_amdgcn_mfma_f32_16x16x32_f16(aF[i], bF[j], acc[i][j], 0, 0, 0);
    }
    __syncthreads();
  }

  int cols[4]; float bv[4];
#pragma unroll
  for (int j = 0; j < 4; ++j) {
    cols[j] = colBase + wc * 64 + j * 16 + l15;
    bv[j] = b1[cols[j]];
  }
#pragma unroll
  for (int i = 0; i < 4; ++i)
#pragma unroll
    for (int q = 0; q < 4; ++q) {
      int rL = wr * 64 + i * 16 + l16 * 4 + q;
      int rG = rowBase + rL;
      const float* ap = AB1 + (size_t)sIF[rL] * 2048;
      const float* bp = AB1 + (size_t)sIS[rL] * 2048 + 1024;
#pragma unroll
      for (int j = 0; j < 4; ++j) {
        int c = cols[j];
        float v = acc[i][j][q] + ap[c] + bp[c] + bv[j];
        h1out[(size_t)rG * 1024 + c] = (_Float16)fmaxf(v, 0.f);
      }
    }
}

// ===========================================================================
// Shared 128x128 EPI-0 GEMM body (2-phase, gload_lds, slot-XOR swizzle)
// ===========================================================================
__device__ __forceinline__ void gemm_body(
    const _Float16* __restrict__ A, const _Float16* __restrict__ Bt,
    float* __restrict__ Cf, int N, int K, int rowBase, int colBase) {
  __shared__ __align__(16) _Float16 sA[8192];
  __shared__ __align__(16) _Float16 sB[8192];
  const int tid = threadIdx.x;
  const int lane = tid & 63;
  const int wave = tid >> 6;
  const int wr = wave >> 1, wc = wave & 1;
  const int l15 = lane & 15, l16 = lane >> 4;
  const int rsw = (l15 >> 1) & 3;
  const int sRow = tid >> 2;
  const int swz8 = (((tid & 3) ^ ((tid >> 3) & 3)) << 3);
  const _Float16* gA = A + (size_t)(rowBase + sRow) * K + swz8;
  const _Float16* gB = Bt + (size_t)(colBase + sRow) * K + swz8;
  _Float16* lA = sA + tid * 8;
  _Float16* lB = sB + tid * 8;

  floatx4 acc[4][4] = {};
  for (int k0 = 0; k0 < K; k0 += 64) {
    GLOAD16(gA + k0,               lA);
    GLOAD16(gA + 64 * K + k0,      lA + 2048);
    GLOAD16(gA + k0 + 32,          lA + 4096);
    GLOAD16(gA + 64 * K + k0 + 32, lA + 6144);
    GLOAD16(gB + k0,               lB);
    GLOAD16(gB + 64 * K + k0,      lB + 2048);
    GLOAD16(gB + k0 + 32,          lB + 4096);
    GLOAD16(gB + 64 * K + k0 + 32, lB + 6144);
    __syncthreads();
#pragma unroll
    for (int h = 0; h < 2; ++h) {
      const int hb = h * 4096;
      half8 aF[4], bF[4];
#pragma unroll
      for (int i = 0; i < 4; ++i)
        aF[i] = *(const half8*)&sA[hb + (wr * 64 + i * 16 + l15) * 32 + ((l16 ^ rsw) << 3)];
#pragma unroll
      for (int j = 0; j < 4; ++j)
        bF[j] = *(const half8*)&sB[hb + (wc * 64 + j * 16 + l15) * 32 + ((l16 ^ rsw) << 3)];
#pragma unroll
      for (int i = 0; i < 4; ++i)
#pragma unroll
        for (int j = 0; j < 4; ++j)
          acc[i][j] = __builtin_amdgcn_mfma_f32_16x16x32_f16(aF[i], bF[j], acc[i][j], 0, 0, 0);
    }
    __syncthreads();
  }
#pragma unroll
  for (int i = 0; i < 4; ++i)
#pragma unroll
    for (int q = 0; q < 4; ++q) {
      int r = rowBase + wr * 64 + i * 16 + l16 * 4 + q;
#pragma unroll
      for (int j = 0; j < 4; ++j) {
        int c = colBase + wc * 64 + j * 16 + l15;
        Cf[(size_t)r * N + c] = acc[i][j][q];
      }
    }
}

__global__ __launch_bounds__(256) void gemm_trio(
    const _Float16* __restrict__ textH, const _Float16* __restrict__ imgH,
    const _Float16* __restrict__ spanH, const _Float16* __restrict__ W1abT,
    float* __restrict__ dotTI, float* __restrict__ dotSI, float* __restrict__ AB1) {
  int bid = blockIdx.x;
  if (bid < 144)      gemm_body(textH, imgH, dotTI, 1152, D_, (bid / 9) * 128, (bid % 9) * 128);
  else if (bid < 252) { int b = bid - 144; gemm_body(spanH, imgH, dotSI, 1152, D_, (b / 9) * 128, (b % 9) * 128); }
  else                { int b = bid - 252; gemm_body(spanH, W1abT, AB1, 2048, D_, (b / 16) * 128, (b % 16) * 128); }
}

// ===========================================================================
// prep_all: cvt (bid<2368) + weight transposes (bid>=2368), one launch
// ===========================================================================
__global__ __launch_bounds__(256) void prep_all(
    const float* __restrict__ text, const float* __restrict__ span,
    const float* __restrict__ img, const float* __restrict__ W1,
    const float* __restrict__ W2, _Float16* __restrict__ textH,
    _Float16* __restrict__ spanH, _Float16* __restrict__ imgH,
    _Float16* __restrict__ W1abT, _Float16* __restrict__ W1cT,
    _Float16* __restrict__ W2T) {
  __shared__ float tbuf[32][33];
  int bid = blockIdx.x;
  if (bid < 2368) {
    long long i = (long long)bid * 256 + threadIdx.x;
    const float* src; _Float16* dst; long long off;
    if (i < 262144)      { src = text; dst = textH; off = i; }
    else if (i < 458752) { src = span; dst = spanH; off = i - 262144; }
    else                 { src = img;  dst = imgH;  off = i - 458752; }
    const float4* p = (const float4*)src + off * 2;
    float4 a = p[0], b = p[1];
    half8 h;
    h[0] = (_Float16)a.x; h[1] = (_Float16)a.y; h[2] = (_Float16)a.z; h[3] = (_Float16)a.w;
    h[4] = (_Float16)b.x; h[5] = (_Float16)b.y; h[6] = (_Float16)b.z; h[7] = (_Float16)b.w;
    *(half8*)(dst + off * 8) = h;
  } else {
    int b = bid - 2368;          // 0..4095
    int z = b >> 10;
    int rem = b & 1023;
    int by = rem >> 5, bx = rem & 31;
    const float* in; _Float16* out;
    switch (z) {
      case 0: in = W1;                 out = W1abT;                 break;
      case 1: in = W1 + 1024 * 1024;   out = W1abT + 1024 * 1024;   break;
      case 2: in = W1 + 2048 * 1024;   out = W1cT;                  break;
      default: in = W2;                out = W2T;                   break;
    }
    const int tx = threadIdx.x & 31, ty = threadIdx.x >> 5;
    const int k0 = by * 32, n0 = bx * 32;
#pragma unroll
    for (int q = 0; q < 4; ++q)
      tbuf[ty + q * 8][tx] = in[(size_t)(k0 + ty + q * 8) * 1024 + n0 + tx];
    __syncthreads();
#pragma unroll
    for (int q = 0; q < 4; ++q)
      out[(size_t)(n0 + ty + q * 8) * 1024 + k0 + tx] = (_Float16)tbuf[tx][ty + q * 8];
  }
}

// ===========================================================================
// sent_extract: bid<1024 = sentence score S[i,j]; bid>=1024 = grounding extract
// ===========================================================================
__global__ __launch_bounds__(64) void sent_extract(
    const float* __restrict__ dotTI, const float* __restrict__ dotSI,
    const float* __restrict__ tmask, const float* __restrict__ imask,
    const float* __restrict__ smask, float* __restrict__ S,
    float* __restrict__ outg) {
  const int bid = blockIdx.x, t = threadIdx.x;
  if (bid >= 1024) {
    int idx = (bid - 1024) * 64 + t;
    if (idx < B_ * NS * LI) {
      int b = idx / (NS * LI);
      int rem = idx - b * (NS * LI);
      int n = rem / LI, l = rem - n * LI;
      float v = dotSI[(size_t)(b * NS + n) * (B_ * LI) + b * LI + l];
      outg[idx] = (smask[b * NS + n] * imask[b * LI + l] != 0.f) ? v : NEGV;
    }
    return;
  }
  const int i = bid >> 5, j = bid & 31;
  __shared__ float red1[64], red2[64];
  const int stride = B_ * LI;
  float e1 = 0.f;
  {
    float tm = tmask[i * NT + t];
    if (tm != 0.f) {
      const float* row = dotTI + (size_t)(i * NT + t) * stride + j * LI;
      float m = -INFINITY;
      for (int l = 0; l < LI; ++l) if (imask[j * LI + l] != 0.f) m = fmaxf(m, row[l]);
      float z = 0.f, w = 0.f;
      for (int l = 0; l < LI; ++l) if (imask[j * LI + l] != 0.f) {
        float d = row[l], p = expf(d - m);
        z += p; w += p * d;
      }
      e1 = w / z;
    }
  }
  red1[t] = e1;
  float e2 = 0.f;
  if (t < LI) {
    float im = imask[j * LI + t];
    if (im != 0.f) {
      const float* col = dotTI + (size_t)(i * NT) * stride + j * LI + t;
      float m = -INFINITY;
      for (int n = 0; n < NT; ++n) if (tmask[i * NT + n] != 0.f) m = fmaxf(m, col[(size_t)n * stride]);
      float z = 0.f, w = 0.f;
      for (int n = 0; n < NT; ++n) if (tmask[i * NT + n] != 0.f) {
        float d = col[(size_t)n * stride], p = expf(d - m);
        z += p; w += p * d;
      }
      e2 = w / z;
    }
  }
  red2[t] = e2;
  __syncthreads();
  if (t == 0) {
    float s1 = 0.f, s2 = 0.f, cn = 0.f, cl = 0.f;
    for (int n = 0; n < NT; ++n) { s1 += red1[n]; cn += tmask[i * NT + n]; }
    for (int l = 0; l < LI; ++l) { s2 += red2[l]; cl += imask[j * LI + l]; }
    S[i * B_ + j] = s1 / cn + s2 / cl;
  }
}

__global__ __launch_bounds__(64) void loss_kernel(
    const float* __restrict__ S, float* __restrict__ out) {
  __shared__ float sS[B_][B_ + 1];
  __shared__ float acc[B_];
  const int t = threadIdx.x;
  for (int e = t; e < B_ * B_; e += 64) sS[e / B_][e % B_] = S[e];
  __syncthreads();
  if (t < B_) {
    float m = -INFINITY;
    for (int j = 0; j < B_; ++j) m = fmaxf(m, sS[t][j]);
    float z = 0.f;
    for (int j = 0; j < B_; ++j) z += expf(sS[t][j] - m);
    float lr = m + logf(z);
    float m2 = -INFINITY;
    for (int i = 0; i < B_; ++i) m2 = fmaxf(m2, sS[i][t]);
    float z2 = 0.f;
    for (int i = 0; i < B_; ++i) z2 += expf(sS[i][t] - m2);
    float lc = m2 + logf(z2);
    acc[t] = 2.f * sS[t][t] - lr - lc;
  }
  __syncthreads();
  if (t == 0) {
    float s = 0.f;
    for (int i = 0; i < B_; ++i) s += acc[i];
    out[0] = -s / (float)B_;
  }
}

extern "C" void kernel_launch(void* const* d_in, const int* in_sizes, int n_in,
                              void* d_out, int out_size, void* d_ws, size_t ws_size,
                              hipStream_t stream) {
  const float* text  = (const float*)d_in[0];
  const float* span  = (const float*)d_in[1];
  const float* img   = (const float*)d_in[2];
  const float* tmask = (const float*)d_in[3];
  const float* smask = (const float*)d_in[4];
  const float* imask = (const float*)d_in[5];
  const float* W1    = (const float*)d_in[6];
  const float* b1    = (const float*)d_in[7];
  const float* W2    = (const float*)d_in[8];
  const float* b2    = (const float*)d_in[9];
  const float* W3    = (const float*)d_in[10];
  const float* b3    = (const float*)d_in[11];

  float* out     = (float*)d_out;
  float* outLoss = out;
  float* outG    = out + 1;
  float* outT    = out + 1 + (size_t)B_ * NS * LI;

  // ---- workspace layout ----
  char* w = (char*)d_ws;
  float*    dotTI = (float*)w;            w += (size_t)(B_*NT) * (B_*LI) * 4;
  float*    dotSI = (float*)w;            w += (size_t)(B_*NS) * (B_*LI) * 4;
  float*    S     = (float*)w;            w += 1024 * 4;
  float*    AB1   = (float*)w;            w += (size_t)1536 * 2048 * 4;
  _Float16* h1    = (_Float16*)w;         w += (size_t)ROWS * 1024 * 2;
  _Float16* textH = (_Float16*)w;         w += (size_t)2048 * 1024 * 2;
  _Float16* spanH = (_Float16*)w;         w += (size_t)1536 * 1024 * 2;
  _Float16* imgH  = (_Float16*)w;         w += (size_t)1152 * 1024 * 2;
  _Float16* W1abT = (_Float16*)w;         w += (size_t)2048 * 1024 * 2;
  _Float16* W1cT  = (_Float16*)w;         w += (size_t)1024 * 1024 * 2;
  _Float16* W2T   = (_Float16*)w;         w += (size_t)1024 * 1024 * 2;
  (void)ws_size; (void)in_sizes; (void)n_in; (void)out_size;

  // ---- prep (cvt + transposes, one launch) + zero scores ----
  prep_all<<<2368 + 4096, 256, 0, stream>>>(text, span, img, W1, W2,
                                            textH, spanH, imgH, W1abT, W1cT, W2T);
  hipMemsetAsync(outT, 0, (size_t)ROWS * sizeof(float), stream);

  // ---- small GEMMs merged: dotTI, dotSI, AB1 ----
  gemm_trio<<<444, 256, 0, stream>>>(textH, imgH, spanH, W1abT, dotTI, dotSI, AB1);
  sent_extract<<<1024 + (B_*NS*LI + 63) / 64, 64, 0, stream>>>(
      dotTI, dotSI, tmask, imask, smask, S, outG);
  loss_kernel<<<1, 64, 0, stream>>>(S, outLoss);

  // ---- pairwise MLP ----
  gemm1_fused<<<8 * CPX * 8, 256, 0, stream>>>(spanH, W1cT, AB1, b1, h1);
  gemm2_8ph<<<564, 512, 0, stream>>>(h1, W2T, outT, b2, W3, b3);
}